// Round 1
// baseline (931.988 us; speedup 1.0000x reference)
//
#include <hip/hip_runtime.h>

#define FH 128
#define NEG_SLOPE 0.2f
#define TM 64
#define TK 64

// ---------------- degree + edge-attr sums (for self-loop fill_value='mean') ----
__global__ void deg_kernel(const int* __restrict__ ei, const float* __restrict__ ea,
                           int* __restrict__ deg, float* __restrict__ easum, int E) {
  int e = blockIdx.x * 256 + threadIdx.x;
  if (e >= E) return;
  int dst = ei[E + e];
  atomicAdd(&deg[dst], 1);
  atomicAdd(&easum[dst], ea[e]);
}

// ---------------- 3-kernel exclusive scan of deg -> rowptr ----------------------
__global__ void scan_blocksum(const int* __restrict__ deg, int* __restrict__ bsum, int n) {
  __shared__ int sm[256];
  int i = blockIdx.x * 256 + threadIdx.x;
  sm[threadIdx.x] = (i < n) ? deg[i] : 0;
  __syncthreads();
  for (int off = 128; off > 0; off >>= 1) {
    if (threadIdx.x < off) sm[threadIdx.x] += sm[threadIdx.x + off];
    __syncthreads();
  }
  if (threadIdx.x == 0) bsum[blockIdx.x] = sm[0];
}

__global__ void scan_bsum(int* __restrict__ bsum, int nb, int* __restrict__ rowptr, int N) {
  __shared__ int sm[1024];
  int t = threadIdx.x;
  int v = (t < nb) ? bsum[t] : 0;
  sm[t] = v;
  __syncthreads();
  for (int off = 1; off < 1024; off <<= 1) {
    int u = (t >= off) ? sm[t - off] : 0;
    __syncthreads();
    sm[t] += u;
    __syncthreads();
  }
  if (t < nb) bsum[t] = sm[t] - v;   // exclusive block offsets
  if (t == 1023) rowptr[N] = sm[1023];
}

__global__ void scan_final(const int* __restrict__ deg, const int* __restrict__ bsum,
                           int* __restrict__ rowptr, int n) {
  __shared__ int sm[256];
  int i = blockIdx.x * 256 + threadIdx.x;
  int v = (i < n) ? deg[i] : 0;
  sm[threadIdx.x] = v;
  __syncthreads();
  for (int off = 1; off < 256; off <<= 1) {
    int u = (threadIdx.x >= off) ? sm[threadIdx.x - off] : 0;
    __syncthreads();
    sm[threadIdx.x] += u;
    __syncthreads();
  }
  if (i < n) rowptr[i] = bsum[blockIdx.x] + sm[threadIdx.x] - v;
}

// ---------------- CSR build (counting scatter) ----------------------------------
__global__ void csr_kernel(const int* __restrict__ ei, const float* __restrict__ ea,
                           const int* __restrict__ rowptr, int* __restrict__ cnt,
                           int* __restrict__ csr_src, float* __restrict__ csr_ea, int E) {
  int e = blockIdx.x * 256 + threadIdx.x;
  if (e >= E) return;
  int src = ei[e], dst = ei[E + e];
  int pos = rowptr[dst] + atomicAdd(&cnt[dst], 1);
  csr_src[pos] = src;
  csr_ea[pos]  = ea[e];
}

// ---------------- c = We . ae (scalar per layer) --------------------------------
__global__ void cvec_kernel(const float* __restrict__ We1, const float* __restrict__ ae1,
                            const float* __restrict__ We2, const float* __restrict__ ae2,
                            float* __restrict__ cv) {
  int l = threadIdx.x;  // 64 lanes
  float s1 = We1[l] * ae1[l] + We1[l + 64] * ae1[l + 64];
  float s2 = We2[l] * ae2[l] + We2[l + 64] * ae2[l + 64];
  for (int off = 32; off; off >>= 1) { s1 += __shfl_down(s1, off); s2 += __shfl_down(s2, off); }
  if (l == 0) { cv[0] = s1; cv[1] = s2; }
}

// ---------------- f32 GEMM: H[M,128] = X[M,K] @ W[K,128] ------------------------
__global__ __launch_bounds__(256) void gemm_kernel(const float* __restrict__ X,
                                                   const float* __restrict__ W,
                                                   float* __restrict__ H, int M, int K) {
  __shared__ float Xs[TK][TM + 4];   // [k][m], +4 keeps float4 alignment
  __shared__ float Ws[TK][FH];
  const int tid = threadIdx.x;
  const int m0  = blockIdx.x * TM;
  const int tm  = (tid >> 4) * 4;    // 16 row-groups of 4
  const int tn  = (tid & 15) * 8;    // 16 col-groups of 8
  float acc[4][8] = {};

  for (int k0 = 0; k0 < K; k0 += TK) {
    // X tile: coalesced along k, stored transposed
    #pragma unroll
    for (int i = tid; i < TM * TK; i += 256) {
      int m = i >> 6, k = i & 63;
      int gm = m0 + m, gk = k0 + k;
      float v = 0.f;
      if (gm < M && gk < K) v = X[(size_t)gm * K + gk];
      Xs[k][m] = v;
    }
    // W tile: float4 coalesced
    #pragma unroll
    for (int i = tid * 4; i < TK * FH; i += 1024) {
      int k = i >> 7, n = i & 127;
      int gk = k0 + k;
      float4 v = make_float4(0.f, 0.f, 0.f, 0.f);
      if (gk < K) v = *(const float4*)&W[(size_t)gk * FH + n];
      *(float4*)&Ws[k][n] = v;
    }
    __syncthreads();
    #pragma unroll 16
    for (int k = 0; k < TK; k++) {
      float4 xa = *(const float4*)&Xs[k][tm];
      float4 w0 = *(const float4*)&Ws[k][tn];
      float4 w1 = *(const float4*)&Ws[k][tn + 4];
      float xr[4] = {xa.x, xa.y, xa.z, xa.w};
      float wr[8] = {w0.x, w0.y, w0.z, w0.w, w1.x, w1.y, w1.z, w1.w};
      #pragma unroll
      for (int r = 0; r < 4; r++)
        #pragma unroll
        for (int c = 0; c < 8; c++) acc[r][c] += xr[r] * wr[c];
    }
    __syncthreads();
  }
  #pragma unroll
  for (int r = 0; r < 4; r++) {
    int gm = m0 + tm + r;
    if (gm < M) {
      *(float4*)&H[(size_t)gm * FH + tn]     = make_float4(acc[r][0], acc[r][1], acc[r][2], acc[r][3]);
      *(float4*)&H[(size_t)gm * FH + tn + 4] = make_float4(acc[r][4], acc[r][5], acc[r][6], acc[r][7]);
    }
  }
}

// ---------------- a_s = h . as, a_d = h . ad (wave per node) --------------------
__global__ void av_kernel(const float* __restrict__ H, const float* __restrict__ avs,
                          const float* __restrict__ avd,
                          float* __restrict__ a_s, float* __restrict__ a_d, int N) {
  int gid = blockIdx.x * 256 + threadIdx.x;
  int node = gid >> 6, lane = threadIdx.x & 63;
  if (node >= N) return;
  float2 h  = *(const float2*)&H[(size_t)node * FH + lane * 2];
  float2 vs = *(const float2*)&avs[lane * 2];
  float2 vd = *(const float2*)&avd[lane * 2];
  float s = h.x * vs.x + h.y * vs.y;
  float d = h.x * vd.x + h.y * vd.y;
  for (int off = 32; off; off >>= 1) { s += __shfl_down(s, off); d += __shfl_down(d, off); }
  if (lane == 0) { a_s[node] = s; a_d[node] = d; }
}

// ---------------- GAT aggregation: single-pass unnormalized softmax -------------
__global__ void agg_kernel(const float* __restrict__ H, const int* __restrict__ rowptr,
                           const int* __restrict__ csr_src, const float* __restrict__ csr_ea,
                           const float* __restrict__ a_s, const float* __restrict__ a_d,
                           const int* __restrict__ deg, const float* __restrict__ easum,
                           const float* __restrict__ cv, int cidx,
                           const float* __restrict__ bias,
                           float* __restrict__ Hout, int N) {
  int gid = blockIdx.x * 256 + threadIdx.x;
  int node = gid >> 6, lane = threadIdx.x & 63;
  if (node >= N) return;
  const float c   = cv[cidx];
  const float adn = a_d[node];
  int beg = rowptr[node], end = rowptr[node + 1];
  float2 acc = make_float2(0.f, 0.f);
  float den = 0.f;
  for (int p = beg; p < end; p++) {
    int src = csr_src[p];                       // wave-uniform broadcast loads
    float alpha = a_s[src] + adn + c * csr_ea[p];
    alpha = (alpha >= 0.f) ? alpha : NEG_SLOPE * alpha;
    float ex = __expf(alpha);
    den += ex;
    float2 h = *(const float2*)&H[(size_t)src * FH + lane * 2];
    acc.x += ex * h.x; acc.y += ex * h.y;
  }
  { // self loop, ea = mean of incoming edge attrs (0 if none)
    float eal = easum[node] / fmaxf((float)deg[node], 1.f);
    float alpha = a_s[node] + adn + c * eal;
    alpha = (alpha >= 0.f) ? alpha : NEG_SLOPE * alpha;
    float ex = __expf(alpha);
    den += ex;
    float2 h = *(const float2*)&H[(size_t)node * FH + lane * 2];
    acc.x += ex * h.x; acc.y += ex * h.y;
  }
  float inv = 1.f / den;
  float2 b = *(const float2*)&bias[lane * 2];
  float o0 = fmaxf(acc.x * inv + b.x, 0.f);   // + bias, ReLU
  float o1 = fmaxf(acc.y * inv + b.y, 0.f);
  *(float2*)&Hout[(size_t)node * FH + lane * 2] = make_float2(o0, o1);
}

// ---------------- node head: b_out and p = h.Ww ----------------------------------
__global__ void node_head_kernel(const float* __restrict__ H, const float* __restrict__ Wb,
                                 const float* __restrict__ bb, const float* __restrict__ Ww,
                                 const float* __restrict__ mask,
                                 float* __restrict__ bout, float* __restrict__ p, int N) {
  int gid = blockIdx.x * 256 + threadIdx.x;
  int node = gid >> 6, lane = threadIdx.x & 63;
  if (node >= N) return;
  float2 h  = *(const float2*)&H[(size_t)node * FH + lane * 2];
  float2 wb = *(const float2*)&Wb[lane * 2];
  float2 ww = *(const float2*)&Ww[lane * 2];
  float sb = h.x * wb.x + h.y * wb.y;
  float sw = h.x * ww.x + h.y * ww.y;
  for (int off = 32; off; off >>= 1) { sb += __shfl_down(sb, off); sw += __shfl_down(sw, off); }
  if (lane == 0) {
    bout[node] = (sb + bb[0]) * mask[node];
    p[node]    = sw;
  }
}

// ---------------- edge head: w = 0.5*(p[src]+p[dst]) + bw ------------------------
__global__ void edge_head_kernel(const int* __restrict__ ei, const float* __restrict__ p,
                                 const float* __restrict__ bw, float* __restrict__ w, int E) {
  int e = blockIdx.x * 256 + threadIdx.x;
  if (e >= E) return;
  w[e] = 0.5f * (p[ei[e]] + p[ei[E + e]]) + bw[0];
}

extern "C" void kernel_launch(void* const* d_in, const int* in_sizes, int n_in,
                              void* d_out, int out_size, void* d_ws, size_t ws_size,
                              hipStream_t stream) {
  (void)n_in; (void)out_size; (void)ws_size;
  const float* x    = (const float*)d_in[0];
  const int*   ei   = (const int*)  d_in[1];
  const float* ea   = (const float*)d_in[2];
  const float* mask = (const float*)d_in[3];
  const float* W1   = (const float*)d_in[4];
  const float* b1   = (const float*)d_in[5];
  const float* as1  = (const float*)d_in[6];
  const float* ad1  = (const float*)d_in[7];
  const float* We1  = (const float*)d_in[8];
  const float* ae1  = (const float*)d_in[9];
  const float* W2   = (const float*)d_in[10];
  const float* b2   = (const float*)d_in[11];
  const float* as2  = (const float*)d_in[12];
  const float* ad2  = (const float*)d_in[13];
  const float* We2  = (const float*)d_in[14];
  const float* ae2  = (const float*)d_in[15];
  const float* Wb   = (const float*)d_in[16];
  const float* bb   = (const float*)d_in[17];
  const float* Ww   = (const float*)d_in[18];
  const float* bw   = (const float*)d_in[19];

  const int N  = in_sizes[3];          // 50000 (input_mask is N x 1)
  const int E  = in_sizes[1] / 2;      // 1600000
  const int K1 = in_sizes[0] / N;      // 503

  // ---- workspace carve-up (256B aligned) ----
  char* ws = (char*)d_ws;
  size_t off = 0;
  auto alloc = [&](size_t bytes) -> char* {
    char* q = ws + off;
    off = (off + bytes + 255) & ~(size_t)255;
    return q;
  };
  const int N4 = (N + 63) & ~63;
  int*   deg    = (int*)  alloc((size_t)3 * N4 * 4);  // deg | cnt | easum (one memset)
  int*   cnt    = deg + N4;
  float* easum  = (float*)(deg + 2 * N4);
  int*   rowptr = (int*)  alloc((size_t)(N + 1) * 4);
  int*   bsum   = (int*)  alloc(1024 * 4);
  int*   csr_src= (int*)  alloc((size_t)E * 4);
  float* csr_ea = (float*)alloc((size_t)E * 4);
  float* a_s    = (float*)alloc((size_t)N * 4);
  float* a_d    = (float*)alloc((size_t)N * 4);
  float* HA     = (float*)alloc((size_t)N * FH * 4);
  float* HB     = (float*)alloc((size_t)N * FH * 4);
  float* pbuf   = (float*)alloc((size_t)N * 4);
  float* cv     = (float*)alloc(8);

  float* w_out = (float*)d_out;        // [E]
  float* b_out = (float*)d_out + E;    // [N]

  hipMemsetAsync(deg, 0, (size_t)3 * N4 * 4, stream);

  const int eb  = (E + 255) / 256;
  const int nb  = (N + 255) / 256;
  const int gb  = (N + TM - 1) / TM;
  const int wbk = ((size_t)N * 64 + 255) / 256;   // wave-per-node launches

  // shared precompute (topology is layer-independent)
  deg_kernel   <<<eb, 256, 0, stream>>>(ei, ea, deg, easum, E);
  scan_blocksum<<<nb, 256, 0, stream>>>(deg, bsum, N);
  scan_bsum    <<<1, 1024, 0, stream>>>(bsum, nb, rowptr, N);
  scan_final   <<<nb, 256, 0, stream>>>(deg, bsum, rowptr, N);
  csr_kernel   <<<eb, 256, 0, stream>>>(ei, ea, rowptr, cnt, csr_src, csr_ea, E);
  cvec_kernel  <<<1, 64, 0, stream>>>(We1, ae1, We2, ae2, cv);

  // layer 1
  gemm_kernel<<<gb, 256, 0, stream>>>(x, W1, HA, N, K1);
  av_kernel  <<<wbk, 256, 0, stream>>>(HA, as1, ad1, a_s, a_d, N);
  agg_kernel <<<wbk, 256, 0, stream>>>(HA, rowptr, csr_src, csr_ea, a_s, a_d,
                                       deg, easum, cv, 0, b1, HB, N);
  // layer 2
  gemm_kernel<<<gb, 256, 0, stream>>>(HB, W2, HA, N, FH);
  av_kernel  <<<wbk, 256, 0, stream>>>(HA, as2, ad2, a_s, a_d, N);
  agg_kernel <<<wbk, 256, 0, stream>>>(HA, rowptr, csr_src, csr_ea, a_s, a_d,
                                       deg, easum, cv, 1, b2, HB, N);
  // heads
  node_head_kernel<<<wbk, 256, 0, stream>>>(HB, Wb, bb, Ww, mask, b_out, pbuf, N);
  edge_head_kernel<<<eb, 256, 0, stream>>>(ei, pbuf, bw, w_out, E);
}

// Round 2
// 805.809 us; speedup vs baseline: 1.1566x; 1.1566x over previous
//
#include <hip/hip_runtime.h>

#define FH 128
#define NEG_SLOPE 0.2f
#define BM 32
#define BN 128
#define BK 32

// ---------------- degree + edge-attr sums (for self-loop fill_value='mean') ----
__global__ void deg_kernel(const int* __restrict__ ei, const float* __restrict__ ea,
                           int* __restrict__ deg, float* __restrict__ easum, int E) {
  int e = blockIdx.x * 256 + threadIdx.x;
  if (e >= E) return;
  int dst = ei[E + e];
  atomicAdd(&deg[dst], 1);
  atomicAdd(&easum[dst], ea[e]);
}

// ---------------- 3-kernel exclusive scan of deg -> rowptr ----------------------
__global__ void scan_blocksum(const int* __restrict__ deg, int* __restrict__ bsum, int n) {
  __shared__ int sm[256];
  int i = blockIdx.x * 256 + threadIdx.x;
  sm[threadIdx.x] = (i < n) ? deg[i] : 0;
  __syncthreads();
  for (int off = 128; off > 0; off >>= 1) {
    if (threadIdx.x < off) sm[threadIdx.x] += sm[threadIdx.x + off];
    __syncthreads();
  }
  if (threadIdx.x == 0) bsum[blockIdx.x] = sm[0];
}

__global__ void scan_bsum(int* __restrict__ bsum, int nb, int* __restrict__ rowptr, int N) {
  __shared__ int sm[1024];
  int t = threadIdx.x;
  int v = (t < nb) ? bsum[t] : 0;
  sm[t] = v;
  __syncthreads();
  for (int off = 1; off < 1024; off <<= 1) {
    int u = (t >= off) ? sm[t - off] : 0;
    __syncthreads();
    sm[t] += u;
    __syncthreads();
  }
  if (t < nb) bsum[t] = sm[t] - v;   // exclusive block offsets
  if (t == 1023) rowptr[N] = sm[1023];
}

__global__ void scan_final(const int* __restrict__ deg, const int* __restrict__ bsum,
                           int* __restrict__ rowptr, int n) {
  __shared__ int sm[256];
  int i = blockIdx.x * 256 + threadIdx.x;
  int v = (i < n) ? deg[i] : 0;
  sm[threadIdx.x] = v;
  __syncthreads();
  for (int off = 1; off < 256; off <<= 1) {
    int u = (threadIdx.x >= off) ? sm[threadIdx.x - off] : 0;
    __syncthreads();
    sm[threadIdx.x] += u;
    __syncthreads();
  }
  if (i < n) rowptr[i] = bsum[blockIdx.x] + sm[threadIdx.x] - v;
}

// ---------------- CSR build (counting scatter) ----------------------------------
__global__ void csr_kernel(const int* __restrict__ ei, const float* __restrict__ ea,
                           const int* __restrict__ rowptr, int* __restrict__ cnt,
                           int* __restrict__ csr_src, float* __restrict__ csr_ea, int E) {
  int e = blockIdx.x * 256 + threadIdx.x;
  if (e >= E) return;
  int src = ei[e], dst = ei[E + e];
  int pos = rowptr[dst] + atomicAdd(&cnt[dst], 1);
  csr_src[pos] = src;
  csr_ea[pos]  = ea[e];
}

// ---------------- c = We . ae (scalar per layer) --------------------------------
__global__ void cvec_kernel(const float* __restrict__ We1, const float* __restrict__ ae1,
                            const float* __restrict__ We2, const float* __restrict__ ae2,
                            float* __restrict__ cv) {
  int l = threadIdx.x;  // 64 lanes
  float s1 = We1[l] * ae1[l] + We1[l + 64] * ae1[l + 64];
  float s2 = We2[l] * ae2[l] + We2[l + 64] * ae2[l + 64];
  for (int off = 32; off; off >>= 1) { s1 += __shfl_down(s1, off); s2 += __shfl_down(s2, off); }
  if (l == 0) { cv[0] = s1; cv[1] = s2; }
}

// ---------------- f32 GEMM + fused a_s/a_d: H[M,128] = X[M,K] @ W[K,128] --------
// BM=32 rows/block, full BN=128, BK=32. 256 threads, 4x4 register tile.
// grid = ceil(M/32) = 1563 blocks (~6/CU), LDS ~21KB (7 blocks/CU fit).
__global__ __launch_bounds__(256, 6) void gemm_fused_kernel(
    const float* __restrict__ X, const float* __restrict__ W,
    const float* __restrict__ avs, const float* __restrict__ avd,
    float* __restrict__ H, float* __restrict__ a_s, float* __restrict__ a_d,
    int M, int K) {
  __shared__ float Xs[BK][BM + 4];   // [k][m], pad->row 144B (16B aligned)
  __shared__ float Ws[BK][BN];       // [k][n]
  const int tid = threadIdx.x;
  const int m0  = blockIdx.x * BM;
  const int tn  = (tid & 31) * 4;    // 32 col-groups of 4
  const int tmg = tid >> 5;          // 8 row-groups of 4
  float acc[4][4] = {};

  for (int k0 = 0; k0 < K; k0 += BK) {
    // stage X tile transposed: lanes run along k (coalesced global reads)
    {
      int kl = tid & 31, ml = tid >> 5;
      int gk = k0 + kl;
      #pragma unroll
      for (int j = 0; j < 4; j++) {
        int m = ml + 8 * j;
        int gm = m0 + m;
        float v = 0.f;
        if (gm < M && gk < K) v = X[(size_t)gm * K + gk];
        Xs[kl][m] = v;
      }
    }
    // stage W tile: float4 coalesced (4096 floats = 1024 float4s, 4/thread)
    {
      #pragma unroll
      for (int i = 0; i < 4; i++) {
        int f4 = tid + i * 256;          // float4 index 0..1023
        int k = f4 >> 5, n = (f4 & 31) * 4;
        int gk = k0 + k;
        float4 v = make_float4(0.f, 0.f, 0.f, 0.f);
        if (gk < K) v = *(const float4*)&W[(size_t)gk * BN + n];
        *(float4*)&Ws[k][n] = v;
      }
    }
    __syncthreads();
    #pragma unroll
    for (int k = 0; k < BK; k++) {
      float4 xv = *(const float4*)&Xs[k][tmg * 4];
      float4 wv = *(const float4*)&Ws[k][tn];
      float xr[4] = {xv.x, xv.y, xv.z, xv.w};
      float wr[4] = {wv.x, wv.y, wv.z, wv.w};
      #pragma unroll
      for (int r = 0; r < 4; r++)
        #pragma unroll
        for (int c = 0; c < 4; c++) acc[r][c] += xr[r] * wr[c];
    }
    __syncthreads();
  }

  // epilogue: store H rows + fused per-row dots with avs/avd
  float4 as4 = *(const float4*)&avs[tn];
  float4 ad4 = *(const float4*)&avd[tn];
  #pragma unroll
  for (int r = 0; r < 4; r++) {
    int gm = m0 + tmg * 4 + r;
    float ps = acc[r][0] * as4.x + acc[r][1] * as4.y + acc[r][2] * as4.z + acc[r][3] * as4.w;
    float pd = acc[r][0] * ad4.x + acc[r][1] * ad4.y + acc[r][2] * ad4.z + acc[r][3] * ad4.w;
    #pragma unroll
    for (int msk = 16; msk; msk >>= 1) {
      ps += __shfl_xor(ps, msk);
      pd += __shfl_xor(pd, msk);
    }
    if (gm < M) {
      *(float4*)&H[(size_t)gm * BN + tn] = make_float4(acc[r][0], acc[r][1], acc[r][2], acc[r][3]);
      if ((tid & 31) == 0) { a_s[gm] = ps; a_d[gm] = pd; }
    }
  }
}

// ---------------- GAT aggregation: single-pass unnormalized softmax -------------
__global__ void agg_kernel(const float* __restrict__ H, const int* __restrict__ rowptr,
                           const int* __restrict__ csr_src, const float* __restrict__ csr_ea,
                           const float* __restrict__ a_s, const float* __restrict__ a_d,
                           const int* __restrict__ deg, const float* __restrict__ easum,
                           const float* __restrict__ cv, int cidx,
                           const float* __restrict__ bias,
                           float* __restrict__ Hout, int N) {
  int gid = blockIdx.x * 256 + threadIdx.x;
  int node = gid >> 6, lane = threadIdx.x & 63;
  if (node >= N) return;
  const float c   = cv[cidx];
  const float adn = a_d[node];
  int beg = rowptr[node], end = rowptr[node + 1];
  float2 acc = make_float2(0.f, 0.f);
  float den = 0.f;
  for (int p = beg; p < end; p++) {
    int src = csr_src[p];                       // wave-uniform broadcast loads
    float alpha = a_s[src] + adn + c * csr_ea[p];
    alpha = (alpha >= 0.f) ? alpha : NEG_SLOPE * alpha;
    float ex = __expf(alpha);
    den += ex;
    float2 h = *(const float2*)&H[(size_t)src * FH + lane * 2];
    acc.x += ex * h.x; acc.y += ex * h.y;
  }
  { // self loop, ea = mean of incoming edge attrs (0 if none)
    float eal = easum[node] / fmaxf((float)deg[node], 1.f);
    float alpha = a_s[node] + adn + c * eal;
    alpha = (alpha >= 0.f) ? alpha : NEG_SLOPE * alpha;
    float ex = __expf(alpha);
    den += ex;
    float2 h = *(const float2*)&H[(size_t)node * FH + lane * 2];
    acc.x += ex * h.x; acc.y += ex * h.y;
  }
  float inv = 1.f / den;
  float2 b = *(const float2*)&bias[lane * 2];
  float o0 = fmaxf(acc.x * inv + b.x, 0.f);   // + bias, ReLU
  float o1 = fmaxf(acc.y * inv + b.y, 0.f);
  *(float2*)&Hout[(size_t)node * FH + lane * 2] = make_float2(o0, o1);
}

// ---------------- node head: b_out and p = h.Ww ----------------------------------
__global__ void node_head_kernel(const float* __restrict__ H, const float* __restrict__ Wb,
                                 const float* __restrict__ bb, const float* __restrict__ Ww,
                                 const float* __restrict__ mask,
                                 float* __restrict__ bout, float* __restrict__ p, int N) {
  int gid = blockIdx.x * 256 + threadIdx.x;
  int node = gid >> 6, lane = threadIdx.x & 63;
  if (node >= N) return;
  float2 h  = *(const float2*)&H[(size_t)node * FH + lane * 2];
  float2 wb = *(const float2*)&Wb[lane * 2];
  float2 ww = *(const float2*)&Ww[lane * 2];
  float sb = h.x * wb.x + h.y * wb.y;
  float sw = h.x * ww.x + h.y * ww.y;
  for (int off = 32; off; off >>= 1) { sb += __shfl_down(sb, off); sw += __shfl_down(sw, off); }
  if (lane == 0) {
    bout[node] = (sb + bb[0]) * mask[node];
    p[node]    = sw;
  }
}

// ---------------- edge head: w = 0.5*(p[src]+p[dst]) + bw ------------------------
__global__ void edge_head_kernel(const int* __restrict__ ei, const float* __restrict__ p,
                                 const float* __restrict__ bw, float* __restrict__ w, int E) {
  int e = blockIdx.x * 256 + threadIdx.x;
  if (e >= E) return;
  w[e] = 0.5f * (p[ei[e]] + p[ei[E + e]]) + bw[0];
}

extern "C" void kernel_launch(void* const* d_in, const int* in_sizes, int n_in,
                              void* d_out, int out_size, void* d_ws, size_t ws_size,
                              hipStream_t stream) {
  (void)n_in; (void)out_size; (void)ws_size;
  const float* x    = (const float*)d_in[0];
  const int*   ei   = (const int*)  d_in[1];
  const float* ea   = (const float*)d_in[2];
  const float* mask = (const float*)d_in[3];
  const float* W1   = (const float*)d_in[4];
  const float* b1   = (const float*)d_in[5];
  const float* as1  = (const float*)d_in[6];
  const float* ad1  = (const float*)d_in[7];
  const float* We1  = (const float*)d_in[8];
  const float* ae1  = (const float*)d_in[9];
  const float* W2   = (const float*)d_in[10];
  const float* b2   = (const float*)d_in[11];
  const float* as2  = (const float*)d_in[12];
  const float* ad2  = (const float*)d_in[13];
  const float* We2  = (const float*)d_in[14];
  const float* ae2  = (const float*)d_in[15];
  const float* Wb   = (const float*)d_in[16];
  const float* bb   = (const float*)d_in[17];
  const float* Ww   = (const float*)d_in[18];
  const float* bw   = (const float*)d_in[19];

  const int N  = in_sizes[3];          // 50000 (input_mask is N x 1)
  const int E  = in_sizes[1] / 2;      // 1600000
  const int K1 = in_sizes[0] / N;      // 503

  // ---- workspace carve-up (256B aligned) ----
  char* ws = (char*)d_ws;
  size_t off = 0;
  auto alloc = [&](size_t bytes) -> char* {
    char* q = ws + off;
    off = (off + bytes + 255) & ~(size_t)255;
    return q;
  };
  const int N4 = (N + 63) & ~63;
  int*   deg    = (int*)  alloc((size_t)3 * N4 * 4);  // deg | cnt | easum (one memset)
  int*   cnt    = deg + N4;
  float* easum  = (float*)(deg + 2 * N4);
  int*   rowptr = (int*)  alloc((size_t)(N + 1) * 4);
  int*   bsum   = (int*)  alloc(1024 * 4);
  int*   csr_src= (int*)  alloc((size_t)E * 4);
  float* csr_ea = (float*)alloc((size_t)E * 4);
  float* a_s    = (float*)alloc((size_t)N * 4);
  float* a_d    = (float*)alloc((size_t)N * 4);
  float* HA     = (float*)alloc((size_t)N * FH * 4);
  float* HB     = (float*)alloc((size_t)N * FH * 4);
  float* pbuf   = (float*)alloc((size_t)N * 4);
  float* cv     = (float*)alloc(8);

  float* w_out = (float*)d_out;        // [E]
  float* b_out = (float*)d_out + E;    // [N]

  hipMemsetAsync(deg, 0, (size_t)3 * N4 * 4, stream);

  const int eb  = (E + 255) / 256;
  const int nb  = (N + 255) / 256;
  const int gb  = (N + BM - 1) / BM;
  const int wbk = ((size_t)N * 64 + 255) / 256;   // wave-per-node launches

  // shared precompute (topology is layer-independent)
  deg_kernel   <<<eb, 256, 0, stream>>>(ei, ea, deg, easum, E);
  scan_blocksum<<<nb, 256, 0, stream>>>(deg, bsum, N);
  scan_bsum    <<<1, 1024, 0, stream>>>(bsum, nb, rowptr, N);
  scan_final   <<<nb, 256, 0, stream>>>(deg, bsum, rowptr, N);
  csr_kernel   <<<eb, 256, 0, stream>>>(ei, ea, rowptr, cnt, csr_src, csr_ea, E);
  cvec_kernel  <<<1, 64, 0, stream>>>(We1, ae1, We2, ae2, cv);

  // layer 1 (GEMM writes H + a_s/a_d fused)
  gemm_fused_kernel<<<gb, 256, 0, stream>>>(x, W1, as1, ad1, HA, a_s, a_d, N, K1);
  agg_kernel <<<wbk, 256, 0, stream>>>(HA, rowptr, csr_src, csr_ea, a_s, a_d,
                                       deg, easum, cv, 0, b1, HB, N);
  // layer 2
  gemm_fused_kernel<<<gb, 256, 0, stream>>>(HB, W2, as2, ad2, HA, a_s, a_d, N, FH);
  agg_kernel <<<wbk, 256, 0, stream>>>(HA, rowptr, csr_src, csr_ea, a_s, a_d,
                                       deg, easum, cv, 1, b2, HB, N);
  // heads
  node_head_kernel<<<wbk, 256, 0, stream>>>(HB, Wb, bb, Ww, mask, b_out, pbuf, N);
  edge_head_kernel<<<eb, 256, 0, stream>>>(ei, pbuf, bw, w_out, E);
}

// Round 3
// 676.005 us; speedup vs baseline: 1.3787x; 1.1920x over previous
//
#include <hip/hip_runtime.h>
#include <hip/hip_fp16.h>

#define FH 128
#define NEG_SLOPE 0.2f
#define BM 32
#define BN 128
#define BK 32

// ---------------- degree + edge-attr sums (for self-loop fill_value='mean') ----
__global__ void deg_kernel(const int* __restrict__ ei, const float* __restrict__ ea,
                           int* __restrict__ deg, float* __restrict__ easum, int E) {
  int e = blockIdx.x * 256 + threadIdx.x;
  if (e >= E) return;
  int dst = ei[E + e];
  atomicAdd(&deg[dst], 1);
  atomicAdd(&easum[dst], ea[e]);
}

// ---------------- 3-kernel exclusive scan of deg -> rowptr ----------------------
__global__ void scan_blocksum(const int* __restrict__ deg, int* __restrict__ bsum, int n) {
  __shared__ int sm[256];
  int i = blockIdx.x * 256 + threadIdx.x;
  sm[threadIdx.x] = (i < n) ? deg[i] : 0;
  __syncthreads();
  for (int off = 128; off > 0; off >>= 1) {
    if (threadIdx.x < off) sm[threadIdx.x] += sm[threadIdx.x + off];
    __syncthreads();
  }
  if (threadIdx.x == 0) bsum[blockIdx.x] = sm[0];
}

__global__ void scan_bsum(int* __restrict__ bsum, int nb, int* __restrict__ rowptr, int N) {
  __shared__ int sm[1024];
  int t = threadIdx.x;
  int v = (t < nb) ? bsum[t] : 0;
  sm[t] = v;
  __syncthreads();
  for (int off = 1; off < 1024; off <<= 1) {
    int u = (t >= off) ? sm[t - off] : 0;
    __syncthreads();
    sm[t] += u;
    __syncthreads();
  }
  if (t < nb) bsum[t] = sm[t] - v;   // exclusive block offsets
  if (t == 1023) rowptr[N] = sm[1023];
}

__global__ void scan_final(const int* __restrict__ deg, const int* __restrict__ bsum,
                           int* __restrict__ rowptr, int n) {
  __shared__ int sm[256];
  int i = blockIdx.x * 256 + threadIdx.x;
  int v = (i < n) ? deg[i] : 0;
  sm[threadIdx.x] = v;
  __syncthreads();
  for (int off = 1; off < 256; off <<= 1) {
    int u = (threadIdx.x >= off) ? sm[threadIdx.x - off] : 0;
    __syncthreads();
    sm[threadIdx.x] += u;
    __syncthreads();
  }
  if (i < n) rowptr[i] = bsum[blockIdx.x] + sm[threadIdx.x] - v;
}

// ---------------- CSR build (counting scatter) ----------------------------------
__global__ void csr_kernel(const int* __restrict__ ei, const float* __restrict__ ea,
                           const int* __restrict__ rowptr, int* __restrict__ cnt,
                           int* __restrict__ csr_src, float* __restrict__ csr_ea, int E) {
  int e = blockIdx.x * 256 + threadIdx.x;
  if (e >= E) return;
  int src = ei[e], dst = ei[E + e];
  int pos = rowptr[dst] + atomicAdd(&cnt[dst], 1);
  csr_src[pos] = src;
  csr_ea[pos]  = ea[e];
}

// ---------------- c = We . ae (scalar per layer) --------------------------------
__global__ void cvec_kernel(const float* __restrict__ We1, const float* __restrict__ ae1,
                            const float* __restrict__ We2, const float* __restrict__ ae2,
                            float* __restrict__ cv) {
  int l = threadIdx.x;  // 64 lanes
  float s1 = We1[l] * ae1[l] + We1[l + 64] * ae1[l + 64];
  float s2 = We2[l] * ae2[l] + We2[l + 64] * ae2[l + 64];
  for (int off = 32; off; off >>= 1) { s1 += __shfl_down(s1, off); s2 += __shfl_down(s2, off); }
  if (l == 0) { cv[0] = s1; cv[1] = s2; }
}

// ---------------- f32 GEMM + fused a_s/a_d; emits fp16 H only -------------------
// H is consumed ONLY by the agg gather -> store fp16 (halves gather bytes).
// a_s/a_d come from the f32 accumulators here (full precision).
__global__ __launch_bounds__(256, 6) void gemm_fused_kernel(
    const float* __restrict__ X, const float* __restrict__ W,
    const float* __restrict__ avs, const float* __restrict__ avd,
    __half* __restrict__ H16, float* __restrict__ a_s, float* __restrict__ a_d,
    int M, int K) {
  __shared__ float Xs[BK][BM + 4];   // [k][m]
  __shared__ float Ws[BK][BN];       // [k][n]
  const int tid = threadIdx.x;
  const int m0  = blockIdx.x * BM;
  const int tn  = (tid & 31) * 4;    // 32 col-groups of 4
  const int tmg = tid >> 5;          // 8 row-groups of 4
  float acc[4][4] = {};

  for (int k0 = 0; k0 < K; k0 += BK) {
    {
      int kl = tid & 31, ml = tid >> 5;
      int gk = k0 + kl;
      #pragma unroll
      for (int j = 0; j < 4; j++) {
        int m = ml + 8 * j;
        int gm = m0 + m;
        float v = 0.f;
        if (gm < M && gk < K) v = X[(size_t)gm * K + gk];
        Xs[kl][m] = v;
      }
    }
    {
      #pragma unroll
      for (int i = 0; i < 4; i++) {
        int f4 = tid + i * 256;          // float4 index 0..1023
        int k = f4 >> 5, n = (f4 & 31) * 4;
        int gk = k0 + k;
        float4 v = make_float4(0.f, 0.f, 0.f, 0.f);
        if (gk < K) v = *(const float4*)&W[(size_t)gk * BN + n];
        *(float4*)&Ws[k][n] = v;
      }
    }
    __syncthreads();
    #pragma unroll
    for (int k = 0; k < BK; k++) {
      float4 xv = *(const float4*)&Xs[k][tmg * 4];
      float4 wv = *(const float4*)&Ws[k][tn];
      float xr[4] = {xv.x, xv.y, xv.z, xv.w};
      float wr[4] = {wv.x, wv.y, wv.z, wv.w};
      #pragma unroll
      for (int r = 0; r < 4; r++)
        #pragma unroll
        for (int c = 0; c < 4; c++) acc[r][c] += xr[r] * wr[c];
    }
    __syncthreads();
  }

  // epilogue: fp16 store + fused per-row dots with avs/avd (f32)
  float4 as4 = *(const float4*)&avs[tn];
  float4 ad4 = *(const float4*)&avd[tn];
  #pragma unroll
  for (int r = 0; r < 4; r++) {
    int gm = m0 + tmg * 4 + r;
    float ps = acc[r][0] * as4.x + acc[r][1] * as4.y + acc[r][2] * as4.z + acc[r][3] * as4.w;
    float pd = acc[r][0] * ad4.x + acc[r][1] * ad4.y + acc[r][2] * ad4.z + acc[r][3] * ad4.w;
    #pragma unroll
    for (int msk = 16; msk; msk >>= 1) {
      ps += __shfl_xor(ps, msk);
      pd += __shfl_xor(pd, msk);
    }
    if (gm < M) {
      __half2 p0 = __floats2half2_rn(acc[r][0], acc[r][1]);
      __half2 p1 = __floats2half2_rn(acc[r][2], acc[r][3]);
      uint2 u;
      u.x = *(unsigned int*)&p0;
      u.y = *(unsigned int*)&p1;
      *(uint2*)&H16[(size_t)gm * BN + tn] = u;
      if ((tid & 31) == 0) { a_s[gm] = ps; a_d[gm] = pd; }
    }
  }
}

// ---------------- GAT aggregation: single-pass unnormalized softmax -------------
// Gathers fp16 H rows (256B/edge), unrolled x2 for memory-level parallelism.
__global__ void agg_kernel(const __half* __restrict__ H16, const int* __restrict__ rowptr,
                           const int* __restrict__ csr_src, const float* __restrict__ csr_ea,
                           const float* __restrict__ a_s, const float* __restrict__ a_d,
                           const int* __restrict__ deg, const float* __restrict__ easum,
                           const float* __restrict__ cv, int cidx,
                           const float* __restrict__ bias,
                           float* __restrict__ Hout, int N) {
  int gid = blockIdx.x * 256 + threadIdx.x;
  int node = gid >> 6, lane = threadIdx.x & 63;
  if (node >= N) return;
  const __half2* __restrict__ H2 = (const __half2*)H16;   // row stride 64 half2
  const float c   = cv[cidx];
  const float adn = a_d[node];
  int beg = rowptr[node], end = rowptr[node + 1];
  float2 acc0 = make_float2(0.f, 0.f), acc1 = make_float2(0.f, 0.f);
  float den0 = 0.f, den1 = 0.f;
  int p = beg;
  for (; p + 1 < end; p += 2) {
    int s0 = csr_src[p], s1 = csr_src[p + 1];
    float e0 = csr_ea[p], e1 = csr_ea[p + 1];
    float as0 = a_s[s0], as1 = a_s[s1];
    __half2 g0 = H2[(size_t)s0 * 64 + lane];
    __half2 g1 = H2[(size_t)s1 * 64 + lane];
    float al0 = as0 + adn + c * e0;
    float al1 = as1 + adn + c * e1;
    al0 = (al0 >= 0.f) ? al0 : NEG_SLOPE * al0;
    al1 = (al1 >= 0.f) ? al1 : NEG_SLOPE * al1;
    float ex0 = __expf(al0), ex1 = __expf(al1);
    float2 h0 = __half22float2(g0), h1 = __half22float2(g1);
    den0 += ex0; den1 += ex1;
    acc0.x += ex0 * h0.x; acc0.y += ex0 * h0.y;
    acc1.x += ex1 * h1.x; acc1.y += ex1 * h1.y;
  }
  if (p < end) {
    int s0 = csr_src[p];
    float al0 = a_s[s0] + adn + c * csr_ea[p];
    al0 = (al0 >= 0.f) ? al0 : NEG_SLOPE * al0;
    float ex0 = __expf(al0);
    float2 h0 = __half22float2(H2[(size_t)s0 * 64 + lane]);
    den0 += ex0;
    acc0.x += ex0 * h0.x; acc0.y += ex0 * h0.y;
  }
  { // self loop, ea = mean of incoming edge attrs (0 if none)
    float eal = easum[node] / fmaxf((float)deg[node], 1.f);
    float alpha = a_s[node] + adn + c * eal;
    alpha = (alpha >= 0.f) ? alpha : NEG_SLOPE * alpha;
    float ex = __expf(alpha);
    float2 h = __half22float2(H2[(size_t)node * 64 + lane]);
    den0 += ex;
    acc0.x += ex * h.x; acc0.y += ex * h.y;
  }
  float inv = 1.f / (den0 + den1);
  float2 b = *(const float2*)&bias[lane * 2];
  float o0 = fmaxf((acc0.x + acc1.x) * inv + b.x, 0.f);   // + bias, ReLU
  float o1 = fmaxf((acc0.y + acc1.y) * inv + b.y, 0.f);
  *(float2*)&Hout[(size_t)node * FH + lane * 2] = make_float2(o0, o1);
}

// ---------------- node head: b_out and p = h.Ww ----------------------------------
__global__ void node_head_kernel(const float* __restrict__ H, const float* __restrict__ Wb,
                                 const float* __restrict__ bb, const float* __restrict__ Ww,
                                 const float* __restrict__ mask,
                                 float* __restrict__ bout, float* __restrict__ p, int N) {
  int gid = blockIdx.x * 256 + threadIdx.x;
  int node = gid >> 6, lane = threadIdx.x & 63;
  if (node >= N) return;
  float2 h  = *(const float2*)&H[(size_t)node * FH + lane * 2];
  float2 wb = *(const float2*)&Wb[lane * 2];
  float2 ww = *(const float2*)&Ww[lane * 2];
  float sb = h.x * wb.x + h.y * wb.y;
  float sw = h.x * ww.x + h.y * ww.y;
  for (int off = 32; off; off >>= 1) { sb += __shfl_down(sb, off); sw += __shfl_down(sw, off); }
  if (lane == 0) {
    bout[node] = (sb + bb[0]) * mask[node];
    p[node]    = sw;
  }
}

// ---------------- edge head: w = 0.5*(p[src]+p[dst]) + bw ------------------------
__global__ void edge_head_kernel(const int* __restrict__ ei, const float* __restrict__ p,
                                 const float* __restrict__ bw, float* __restrict__ w, int E) {
  int e = blockIdx.x * 256 + threadIdx.x;
  if (e >= E) return;
  w[e] = 0.5f * (p[ei[e]] + p[ei[E + e]]) + bw[0];
}

extern "C" void kernel_launch(void* const* d_in, const int* in_sizes, int n_in,
                              void* d_out, int out_size, void* d_ws, size_t ws_size,
                              hipStream_t stream) {
  (void)n_in; (void)out_size; (void)ws_size;
  const float* x    = (const float*)d_in[0];
  const int*   ei   = (const int*)  d_in[1];
  const float* ea   = (const float*)d_in[2];
  const float* mask = (const float*)d_in[3];
  const float* W1   = (const float*)d_in[4];
  const float* b1   = (const float*)d_in[5];
  const float* as1  = (const float*)d_in[6];
  const float* ad1  = (const float*)d_in[7];
  const float* We1  = (const float*)d_in[8];
  const float* ae1  = (const float*)d_in[9];
  const float* W2   = (const float*)d_in[10];
  const float* b2   = (const float*)d_in[11];
  const float* as2  = (const float*)d_in[12];
  const float* ad2  = (const float*)d_in[13];
  const float* We2  = (const float*)d_in[14];
  const float* ae2  = (const float*)d_in[15];
  const float* Wb   = (const float*)d_in[16];
  const float* bb   = (const float*)d_in[17];
  const float* Ww   = (const float*)d_in[18];
  const float* bw   = (const float*)d_in[19];

  const int N  = in_sizes[3];          // 50000 (input_mask is N x 1)
  const int E  = in_sizes[1] / 2;      // 1600000
  const int K1 = in_sizes[0] / N;      // 503

  // ---- workspace carve-up (256B aligned) ----
  char* ws = (char*)d_ws;
  size_t off = 0;
  auto alloc = [&](size_t bytes) -> char* {
    char* q = ws + off;
    off = (off + bytes + 255) & ~(size_t)255;
    return q;
  };
  const int N4 = (N + 63) & ~63;
  int*   deg    = (int*)  alloc((size_t)3 * N4 * 4);  // deg | cnt | easum (one memset)
  int*   cnt    = deg + N4;
  float* easum  = (float*)(deg + 2 * N4);
  int*   rowptr = (int*)  alloc((size_t)(N + 1) * 4);
  int*   bsum   = (int*)  alloc(1024 * 4);
  int*   csr_src= (int*)  alloc((size_t)E * 4);
  float* csr_ea = (float*)alloc((size_t)E * 4);
  float* a_s    = (float*)alloc((size_t)N * 4);
  float* a_d    = (float*)alloc((size_t)N * 4);
  __half* H16   = (__half*)alloc((size_t)N * FH * 2);  // fp16 GEMM out (both layers)
  float* HB     = (float*)alloc((size_t)N * FH * 4);   // agg out (f32)
  float* pbuf   = (float*)alloc((size_t)N * 4);
  float* cv     = (float*)alloc(8);

  float* w_out = (float*)d_out;        // [E]
  float* b_out = (float*)d_out + E;    // [N]

  hipMemsetAsync(deg, 0, (size_t)3 * N4 * 4, stream);

  const int eb  = (E + 255) / 256;
  const int nb  = (N + 255) / 256;
  const int gb  = (N + BM - 1) / BM;
  const int wbk = ((size_t)N * 64 + 255) / 256;   // wave-per-node launches

  // shared precompute (topology is layer-independent)
  deg_kernel   <<<eb, 256, 0, stream>>>(ei, ea, deg, easum, E);
  scan_blocksum<<<nb, 256, 0, stream>>>(deg, bsum, N);
  scan_bsum    <<<1, 1024, 0, stream>>>(bsum, nb, rowptr, N);
  scan_final   <<<nb, 256, 0, stream>>>(deg, bsum, rowptr, N);
  csr_kernel   <<<eb, 256, 0, stream>>>(ei, ea, rowptr, cnt, csr_src, csr_ea, E);
  cvec_kernel  <<<1, 64, 0, stream>>>(We1, ae1, We2, ae2, cv);

  // layer 1 (GEMM writes fp16 H + fused a_s/a_d)
  gemm_fused_kernel<<<gb, 256, 0, stream>>>(x, W1, as1, ad1, H16, a_s, a_d, N, K1);
  agg_kernel <<<wbk, 256, 0, stream>>>(H16, rowptr, csr_src, csr_ea, a_s, a_d,
                                       deg, easum, cv, 0, b1, HB, N);
  // layer 2
  gemm_fused_kernel<<<gb, 256, 0, stream>>>(HB, W2, as2, ad2, H16, a_s, a_d, N, FH);
  agg_kernel <<<wbk, 256, 0, stream>>>(H16, rowptr, csr_src, csr_ea, a_s, a_d,
                                       deg, easum, cv, 1, b2, HB, N);
  // heads (HB now holds layer-2 output)
  node_head_kernel<<<wbk, 256, 0, stream>>>(HB, Wb, bb, Ww, mask, b_out, pbuf, N);
  edge_head_kernel<<<eb, 256, 0, stream>>>(ei, pbuf, bw, w_out, E);
}

// Round 4
// 591.175 us; speedup vs baseline: 1.5765x; 1.1435x over previous
//
#include <hip/hip_runtime.h>
#include <hip/hip_fp16.h>

#define FH 128
#define NEG_SLOPE 0.2f
#define GBM 64
#define GBK 64

typedef _Float16 f16x8 __attribute__((ext_vector_type(8)));
typedef float f32x4 __attribute__((ext_vector_type(4)));

// ---------------- degree + edge-attr sums (for self-loop fill_value='mean') ----
__global__ void deg_kernel(const int* __restrict__ ei, const float* __restrict__ ea,
                           int* __restrict__ deg, float* __restrict__ easum, int E) {
  int e = blockIdx.x * 256 + threadIdx.x;
  if (e >= E) return;
  int dst = ei[E + e];
  atomicAdd(&deg[dst], 1);
  atomicAdd(&easum[dst], ea[e]);
}

// ---------------- 3-kernel exclusive scan of deg -> rowptr ----------------------
__global__ void scan_blocksum(const int* __restrict__ deg, int* __restrict__ bsum, int n) {
  __shared__ int sm[256];
  int i = blockIdx.x * 256 + threadIdx.x;
  sm[threadIdx.x] = (i < n) ? deg[i] : 0;
  __syncthreads();
  for (int off = 128; off > 0; off >>= 1) {
    if (threadIdx.x < off) sm[threadIdx.x] += sm[threadIdx.x + off];
    __syncthreads();
  }
  if (threadIdx.x == 0) bsum[blockIdx.x] = sm[0];
}

__global__ void scan_bsum(int* __restrict__ bsum, int nb, int* __restrict__ rowptr, int N) {
  __shared__ int sm[1024];
  int t = threadIdx.x;
  int v = (t < nb) ? bsum[t] : 0;
  sm[t] = v;
  __syncthreads();
  for (int off = 1; off < 1024; off <<= 1) {
    int u = (t >= off) ? sm[t - off] : 0;
    __syncthreads();
    sm[t] += u;
    __syncthreads();
  }
  if (t < nb) bsum[t] = sm[t] - v;   // exclusive block offsets
  if (t == 1023) rowptr[N] = sm[1023];
}

__global__ void scan_final(const int* __restrict__ deg, const int* __restrict__ bsum,
                           int* __restrict__ rowptr, int n) {
  __shared__ int sm[256];
  int i = blockIdx.x * 256 + threadIdx.x;
  int v = (i < n) ? deg[i] : 0;
  sm[threadIdx.x] = v;
  __syncthreads();
  for (int off = 1; off < 256; off <<= 1) {
    int u = (threadIdx.x >= off) ? sm[threadIdx.x - off] : 0;
    __syncthreads();
    sm[threadIdx.x] += u;
    __syncthreads();
  }
  if (i < n) rowptr[i] = bsum[blockIdx.x] + sm[threadIdx.x] - v;
}

// ---------------- CSR build (counting scatter) ----------------------------------
__global__ void csr_kernel(const int* __restrict__ ei, const float* __restrict__ ea,
                           const int* __restrict__ rowptr, int* __restrict__ cnt,
                           int* __restrict__ csr_src, float* __restrict__ csr_ea, int E) {
  int e = blockIdx.x * 256 + threadIdx.x;
  if (e >= E) return;
  int src = ei[e], dst = ei[E + e];
  int pos = rowptr[dst] + atomicAdd(&cnt[dst], 1);
  csr_src[pos] = src;
  csr_ea[pos]  = ea[e];
}

// ---------------- c = We . ae (scalar per layer) --------------------------------
__global__ void cvec_kernel(const float* __restrict__ We1, const float* __restrict__ ae1,
                            const float* __restrict__ We2, const float* __restrict__ ae2,
                            float* __restrict__ cv) {
  int l = threadIdx.x;  // 64 lanes
  float s1 = We1[l] * ae1[l] + We1[l + 64] * ae1[l + 64];
  float s2 = We2[l] * ae2[l] + We2[l + 64] * ae2[l + 64];
  for (int off = 32; off; off >>= 1) { s1 += __shfl_down(s1, off); s2 += __shfl_down(s2, off); }
  if (l == 0) { cv[0] = s1; cv[1] = s2; }
}

// ---------------- W (K x 128) -> Wt fp16 [128][Kpad] (transposed, zero-padded) ---
__global__ void wcvt_kernel(const float* __restrict__ W, __half* __restrict__ Wt,
                            int K, int Kpad) {
  int idx = blockIdx.x * 256 + threadIdx.x;
  if (idx >= 128 * Kpad) return;
  int n = idx / Kpad, k = idx - n * Kpad;
  Wt[idx] = (k < K) ? __float2half(W[(size_t)k * 128 + n]) : __float2half(0.f);
}

// ---------------- MFMA fp16 GEMM: H16[M][128] = X[M][K] @ Wt^T ------------------
// 256 threads = 4 waves; wave w owns rows m0+16w..+15 (A-rows wave-exclusive ->
// A direct global->reg, fp16 convert in regs). B staged to LDS in fragment order.
// Frag layout (m89/m92-verified): A/B elem j <-> k=(l>>4)*8+j; C/D row=(l>>4)*4+r,
// col=l&15.
__global__ __launch_bounds__(256, 4) void mfma_gemm_kernel(
    const float* __restrict__ X, const __half* __restrict__ Wt_,
    __half* __restrict__ H16, int M, int K, int Kpad) {
  __shared__ _Float16 Bl[2 * 8 * 64 * 8];   // [kt][nt][frag-lane][j] = 16 KB
  const _Float16* __restrict__ Wt = (const _Float16*)Wt_;
  const int tid  = threadIdx.x;
  const int lane = tid & 63;
  const int w    = tid >> 6;
  const int m0   = blockIdx.x * GBM;

  f32x4 acc[8];
  #pragma unroll
  for (int i = 0; i < 8; i++) acc[i] = (f32x4){0.f, 0.f, 0.f, 0.f};

  const int arow   = m0 + w * 16 + (lane & 15);
  const int arow_c = arow < M ? arow : (M - 1);
  const float* __restrict__ Xrow = X + (size_t)arow_c * K;
  const int kgrp = (lane >> 4) * 8;          // 0,8,16,24

  const int sg = tid & 7, snb = tid >> 3;    // staging coords: g=k-octet, n-base

  for (int k0 = 0; k0 < Kpad; k0 += GBK) {
    // ---- stage B tile (64k x 128n) into fragment-order LDS: 4 x b128/thread ----
    #pragma unroll
    for (int i = 0; i < 4; i++) {
      int n = snb + 32 * i;
      f16x8 v = *(const f16x8*)(Wt + (size_t)n * Kpad + k0 + sg * 8);
      int kt = sg >> 2, nt = n >> 4;
      int fl = (n & 15) + (sg & 3) * 16;
      *(f16x8*)&Bl[((kt * 8 + nt) * 64 + fl) * 8] = v;
    }
    __syncthreads();
    const bool fast = (k0 + GBK <= K);
    #pragma unroll
    for (int kt = 0; kt < 2; kt++) {
      int kb = k0 + kt * 32 + kgrp;
      f16x8 af;
      if (fast) {
        #pragma unroll
        for (int j = 0; j < 8; j++) af[j] = (_Float16)Xrow[kb + j];
      } else {
        #pragma unroll
        for (int j = 0; j < 8; j++)
          af[j] = (kb + j < K) ? (_Float16)Xrow[kb + j] : (_Float16)0.f;
      }
      #pragma unroll
      for (int nt = 0; nt < 8; nt++) {
        f16x8 bf = *(const f16x8*)&Bl[((kt * 8 + nt) * 64 + lane) * 8];
        acc[nt] = __builtin_amdgcn_mfma_f32_16x16x32_f16(af, bf, acc[nt], 0, 0, 0);
      }
    }
    __syncthreads();
  }

  // C store (fp16): lane -> rows (l>>4)*4+r, col l&15 (+16 per nt)
  const int rbase = m0 + w * 16 + (lane >> 4) * 4;
  const int col   = lane & 15;
  #pragma unroll
  for (int r = 0; r < 4; r++) {
    int gm = rbase + r;
    if (gm < M) {
      #pragma unroll
      for (int nt = 0; nt < 8; nt++)
        H16[(size_t)gm * FH + nt * 16 + col] = __float2half(acc[nt][r]);
    }
  }
}

// ---------------- a_s = h . as, a_d = h . ad (wave per node, fp16 H) ------------
__global__ void av16_kernel(const __half* __restrict__ H16, const float* __restrict__ avs,
                            const float* __restrict__ avd,
                            float* __restrict__ a_s, float* __restrict__ a_d, int N) {
  int gid = blockIdx.x * 256 + threadIdx.x;
  int node = gid >> 6, lane = threadIdx.x & 63;
  if (node >= N) return;
  float2 h  = __half22float2(((const __half2*)H16)[(size_t)node * 64 + lane]);
  float2 vs = *(const float2*)&avs[lane * 2];
  float2 vd = *(const float2*)&avd[lane * 2];
  float s = h.x * vs.x + h.y * vs.y;
  float d = h.x * vd.x + h.y * vd.y;
  for (int off = 32; off; off >>= 1) { s += __shfl_down(s, off); d += __shfl_down(d, off); }
  if (lane == 0) { a_s[node] = s; a_d[node] = d; }
}

// ---------------- GAT aggregation: single-pass unnormalized softmax -------------
__global__ void agg_kernel(const __half* __restrict__ H16, const int* __restrict__ rowptr,
                           const int* __restrict__ csr_src, const float* __restrict__ csr_ea,
                           const float* __restrict__ a_s, const float* __restrict__ a_d,
                           const int* __restrict__ deg, const float* __restrict__ easum,
                           const float* __restrict__ cv, int cidx,
                           const float* __restrict__ bias,
                           float* __restrict__ Hout, int N) {
  int gid = blockIdx.x * 256 + threadIdx.x;
  int node = gid >> 6, lane = threadIdx.x & 63;
  if (node >= N) return;
  const __half2* __restrict__ H2 = (const __half2*)H16;   // row stride 64 half2
  const float c   = cv[cidx];
  const float adn = a_d[node];
  int beg = rowptr[node], end = rowptr[node + 1];
  float2 acc0 = make_float2(0.f, 0.f), acc1 = make_float2(0.f, 0.f);
  float den0 = 0.f, den1 = 0.f;
  int p = beg;
  for (; p + 1 < end; p += 2) {
    int s0 = csr_src[p], s1 = csr_src[p + 1];
    float e0 = csr_ea[p], e1 = csr_ea[p + 1];
    float as0 = a_s[s0], as1 = a_s[s1];
    __half2 g0 = H2[(size_t)s0 * 64 + lane];
    __half2 g1 = H2[(size_t)s1 * 64 + lane];
    float al0 = as0 + adn + c * e0;
    float al1 = as1 + adn + c * e1;
    al0 = (al0 >= 0.f) ? al0 : NEG_SLOPE * al0;
    al1 = (al1 >= 0.f) ? al1 : NEG_SLOPE * al1;
    float ex0 = __expf(al0), ex1 = __expf(al1);
    float2 h0 = __half22float2(g0), h1 = __half22float2(g1);
    den0 += ex0; den1 += ex1;
    acc0.x += ex0 * h0.x; acc0.y += ex0 * h0.y;
    acc1.x += ex1 * h1.x; acc1.y += ex1 * h1.y;
  }
  if (p < end) {
    int s0 = csr_src[p];
    float al0 = a_s[s0] + adn + c * csr_ea[p];
    al0 = (al0 >= 0.f) ? al0 : NEG_SLOPE * al0;
    float ex0 = __expf(al0);
    float2 h0 = __half22float2(H2[(size_t)s0 * 64 + lane]);
    den0 += ex0;
    acc0.x += ex0 * h0.x; acc0.y += ex0 * h0.y;
  }
  { // self loop, ea = mean of incoming edge attrs (0 if none)
    float eal = easum[node] / fmaxf((float)deg[node], 1.f);
    float alpha = a_s[node] + adn + c * eal;
    alpha = (alpha >= 0.f) ? alpha : NEG_SLOPE * alpha;
    float ex = __expf(alpha);
    float2 h = __half22float2(H2[(size_t)node * 64 + lane]);
    den0 += ex;
    acc0.x += ex * h.x; acc0.y += ex * h.y;
  }
  float inv = 1.f / (den0 + den1);
  float2 b = *(const float2*)&bias[lane * 2];
  float o0 = fmaxf((acc0.x + acc1.x) * inv + b.x, 0.f);   // + bias, ReLU
  float o1 = fmaxf((acc0.y + acc1.y) * inv + b.y, 0.f);
  *(float2*)&Hout[(size_t)node * FH + lane * 2] = make_float2(o0, o1);
}

// ---------------- node head: b_out and p = h.Ww ----------------------------------
__global__ void node_head_kernel(const float* __restrict__ H, const float* __restrict__ Wb,
                                 const float* __restrict__ bb, const float* __restrict__ Ww,
                                 const float* __restrict__ mask,
                                 float* __restrict__ bout, float* __restrict__ p, int N) {
  int gid = blockIdx.x * 256 + threadIdx.x;
  int node = gid >> 6, lane = threadIdx.x & 63;
  if (node >= N) return;
  float2 h  = *(const float2*)&H[(size_t)node * FH + lane * 2];
  float2 wb = *(const float2*)&Wb[lane * 2];
  float2 ww = *(const float2*)&Ww[lane * 2];
  float sb = h.x * wb.x + h.y * wb.y;
  float sw = h.x * ww.x + h.y * ww.y;
  for (int off = 32; off; off >>= 1) { sb += __shfl_down(sb, off); sw += __shfl_down(sw, off); }
  if (lane == 0) {
    bout[node] = (sb + bb[0]) * mask[node];
    p[node]    = sw;
  }
}

// ---------------- edge head: w = 0.5*(p[src]+p[dst]) + bw ------------------------
__global__ void edge_head_kernel(const int* __restrict__ ei, const float* __restrict__ p,
                                 const float* __restrict__ bw, float* __restrict__ w, int E) {
  int e = blockIdx.x * 256 + threadIdx.x;
  if (e >= E) return;
  w[e] = 0.5f * (p[ei[e]] + p[ei[E + e]]) + bw[0];
}

extern "C" void kernel_launch(void* const* d_in, const int* in_sizes, int n_in,
                              void* d_out, int out_size, void* d_ws, size_t ws_size,
                              hipStream_t stream) {
  (void)n_in; (void)out_size; (void)ws_size;
  const float* x    = (const float*)d_in[0];
  const int*   ei   = (const int*)  d_in[1];
  const float* ea   = (const float*)d_in[2];
  const float* mask = (const float*)d_in[3];
  const float* W1   = (const float*)d_in[4];
  const float* b1   = (const float*)d_in[5];
  const float* as1  = (const float*)d_in[6];
  const float* ad1  = (const float*)d_in[7];
  const float* We1  = (const float*)d_in[8];
  const float* ae1  = (const float*)d_in[9];
  const float* W2   = (const float*)d_in[10];
  const float* b2   = (const float*)d_in[11];
  const float* as2  = (const float*)d_in[12];
  const float* ad2  = (const float*)d_in[13];
  const float* We2  = (const float*)d_in[14];
  const float* ae2  = (const float*)d_in[15];
  const float* Wb   = (const float*)d_in[16];
  const float* bb   = (const float*)d_in[17];
  const float* Ww   = (const float*)d_in[18];
  const float* bw   = (const float*)d_in[19];

  const int N  = in_sizes[3];          // 50000
  const int E  = in_sizes[1] / 2;      // 1600000
  const int K1 = in_sizes[0] / N;      // 503
  const int K1p = (K1 + GBK - 1) & ~(GBK - 1);   // 512

  // ---- workspace carve-up (256B aligned) ----
  char* ws = (char*)d_ws;
  size_t off = 0;
  auto alloc = [&](size_t bytes) -> char* {
    char* q = ws + off;
    off = (off + bytes + 255) & ~(size_t)255;
    return q;
  };
  const int N4 = (N + 63) & ~63;
  int*   deg    = (int*)  alloc((size_t)3 * N4 * 4);  // deg | cnt | easum
  int*   cnt    = deg + N4;
  float* easum  = (float*)(deg + 2 * N4);
  int*   rowptr = (int*)  alloc((size_t)(N + 1) * 4);
  int*   bsum   = (int*)  alloc(1024 * 4);
  int*   csr_src= (int*)  alloc((size_t)E * 4);
  float* csr_ea = (float*)alloc((size_t)E * 4);
  float* a_s    = (float*)alloc((size_t)N * 4);
  float* a_d    = (float*)alloc((size_t)N * 4);
  __half* H16   = (__half*)alloc((size_t)N * FH * 2);  // fp16 GEMM out
  float* HB     = (float*)alloc((size_t)N * FH * 4);   // agg out (f32)
  float* pbuf   = (float*)alloc((size_t)N * 4);
  float* cv     = (float*)alloc(8);
  __half* W1t   = (__half*)alloc((size_t)FH * K1p * 2);
  __half* W2t   = (__half*)alloc((size_t)FH * FH * 2);

  float* w_out = (float*)d_out;        // [E]
  float* b_out = (float*)d_out + E;    // [N]

  hipMemsetAsync(deg, 0, (size_t)3 * N4 * 4, stream);

  const int eb  = (E + 255) / 256;
  const int nb  = (N + 255) / 256;
  const int gb  = (N + GBM - 1) / GBM;
  const int wbk = ((size_t)N * 64 + 255) / 256;   // wave-per-node launches

  // shared precompute (topology is layer-independent)
  deg_kernel   <<<eb, 256, 0, stream>>>(ei, ea, deg, easum, E);
  scan_blocksum<<<nb, 256, 0, stream>>>(deg, bsum, N);
  scan_bsum    <<<1, 1024, 0, stream>>>(bsum, nb, rowptr, N);
  scan_final   <<<nb, 256, 0, stream>>>(deg, bsum, rowptr, N);
  csr_kernel   <<<eb, 256, 0, stream>>>(ei, ea, rowptr, cnt, csr_src, csr_ea, E);
  cvec_kernel  <<<1, 64, 0, stream>>>(We1, ae1, We2, ae2, cv);
  wcvt_kernel  <<<(128 * K1p + 255) / 256, 256, 0, stream>>>(W1, W1t, K1, K1p);
  wcvt_kernel  <<<(128 * FH + 255) / 256, 256, 0, stream>>>(W2, W2t, FH, FH);

  // layer 1
  mfma_gemm_kernel<<<gb, 256, 0, stream>>>(x, W1t, H16, N, K1, K1p);
  av16_kernel <<<wbk, 256, 0, stream>>>(H16, as1, ad1, a_s, a_d, N);
  agg_kernel  <<<wbk, 256, 0, stream>>>(H16, rowptr, csr_src, csr_ea, a_s, a_d,
                                        deg, easum, cv, 0, b1, HB, N);
  // layer 2
  mfma_gemm_kernel<<<gb, 256, 0, stream>>>(HB, W2t, H16, N, FH, FH);
  av16_kernel <<<wbk, 256, 0, stream>>>(H16, as2, ad2, a_s, a_d, N);
  agg_kernel  <<<wbk, 256, 0, stream>>>(H16, rowptr, csr_src, csr_ea, a_s, a_d,
                                        deg, easum, cv, 1, b2, HB, N);
  // heads (HB holds layer-2 output, f32)
  node_head_kernel<<<wbk, 256, 0, stream>>>(HB, Wb, bb, Ww, mask, b_out, pbuf, N);
  edge_head_kernel<<<eb, 256, 0, stream>>>(ei, pbuf, bw, w_out, E);
}

// Round 5
// 346.339 us; speedup vs baseline: 2.6910x; 1.7069x over previous
//
#include <hip/hip_runtime.h>
#include <hip/hip_fp16.h>

#define FH 128
#define NEG_SLOPE 0.2f
#define GBM 64
#define GBK 64

typedef _Float16 f16x8 __attribute__((ext_vector_type(8)));
typedef float f32x4 __attribute__((ext_vector_type(4)));

// ---------------- pass A: rank[e] = running count per dst (ONE atomic/edge) -----
__global__ void rank_kernel(const int* __restrict__ ei, int* __restrict__ cnt,
                            unsigned short* __restrict__ rank, int E) {
  int e = blockIdx.x * 256 + threadIdx.x;
  if (e >= E) return;
  int dst = ei[E + e];
  rank[e] = (unsigned short)atomicAdd(&cnt[dst], 1);
}

// ---------------- 3-kernel exclusive scan of cnt -> rowptr ----------------------
__global__ void scan_blocksum(const int* __restrict__ deg, int* __restrict__ bsum, int n) {
  __shared__ int sm[256];
  int i = blockIdx.x * 256 + threadIdx.x;
  sm[threadIdx.x] = (i < n) ? deg[i] : 0;
  __syncthreads();
  for (int off = 128; off > 0; off >>= 1) {
    if (threadIdx.x < off) sm[threadIdx.x] += sm[threadIdx.x + off];
    __syncthreads();
  }
  if (threadIdx.x == 0) bsum[blockIdx.x] = sm[0];
}

__global__ void scan_bsum(int* __restrict__ bsum, int nb, int* __restrict__ rowptr, int N) {
  __shared__ int sm[1024];
  int t = threadIdx.x;
  int v = (t < nb) ? bsum[t] : 0;
  sm[t] = v;
  __syncthreads();
  for (int off = 1; off < 1024; off <<= 1) {
    int u = (t >= off) ? sm[t - off] : 0;
    __syncthreads();
    sm[t] += u;
    __syncthreads();
  }
  if (t < nb) bsum[t] = sm[t] - v;   // exclusive block offsets
  if (t == 1023) rowptr[N] = sm[1023];
}

__global__ void scan_final(const int* __restrict__ deg, const int* __restrict__ bsum,
                           int* __restrict__ rowptr, int n) {
  __shared__ int sm[256];
  int i = blockIdx.x * 256 + threadIdx.x;
  int v = (i < n) ? deg[i] : 0;
  sm[threadIdx.x] = v;
  __syncthreads();
  for (int off = 1; off < 256; off <<= 1) {
    int u = (threadIdx.x >= off) ? sm[threadIdx.x - off] : 0;
    __syncthreads();
    sm[threadIdx.x] += u;
    __syncthreads();
  }
  if (i < n) rowptr[i] = bsum[blockIdx.x] + sm[threadIdx.x] - v;
}

// ---------------- pass B: atomic-free CSR placement, packed 4B entries ----------
// entry = (src << 16) | fp16(ea)   [N=50000 < 2^16]
__global__ void place_kernel(const int* __restrict__ ei, const float* __restrict__ ea,
                             const int* __restrict__ rowptr,
                             const unsigned short* __restrict__ rank,
                             unsigned int* __restrict__ pack, int E) {
  int e = blockIdx.x * 256 + threadIdx.x;
  if (e >= E) return;
  int src = ei[e], dst = ei[E + e];
  int pos = rowptr[dst] + rank[e];
  unsigned short h = __half_as_ushort(__float2half(ea[e]));
  pack[pos] = ((unsigned int)src << 16) | h;
}

// ---------------- c = We . ae (scalar per layer) --------------------------------
__global__ void cvec_kernel(const float* __restrict__ We1, const float* __restrict__ ae1,
                            const float* __restrict__ We2, const float* __restrict__ ae2,
                            float* __restrict__ cv) {
  int l = threadIdx.x;  // 64 lanes
  float s1 = We1[l] * ae1[l] + We1[l + 64] * ae1[l + 64];
  float s2 = We2[l] * ae2[l] + We2[l + 64] * ae2[l + 64];
  for (int off = 32; off; off >>= 1) { s1 += __shfl_down(s1, off); s2 += __shfl_down(s2, off); }
  if (l == 0) { cv[0] = s1; cv[1] = s2; }
}

// ---------------- W (K x 128) -> Wt fp16 [128][Kpad] (transposed, zero-padded) ---
__global__ void wcvt_kernel(const float* __restrict__ W, __half* __restrict__ Wt,
                            int K, int Kpad) {
  int idx = blockIdx.x * 256 + threadIdx.x;
  if (idx >= 128 * Kpad) return;
  int n = idx / Kpad, k = idx - n * Kpad;
  Wt[idx] = (k < K) ? __float2half(W[(size_t)k * 128 + n]) : __float2half(0.f);
}

// ---------------- MFMA fp16 GEMM: H16[M][128] = X[M][K] @ Wt^T ------------------
__global__ __launch_bounds__(256, 4) void mfma_gemm_kernel(
    const float* __restrict__ X, const __half* __restrict__ Wt_,
    __half* __restrict__ H16, int M, int K, int Kpad) {
  __shared__ _Float16 Bl[2 * 8 * 64 * 8];   // [kt][nt][frag-lane][j] = 16 KB
  const _Float16* __restrict__ Wt = (const _Float16*)Wt_;
  const int tid  = threadIdx.x;
  const int lane = tid & 63;
  const int w    = tid >> 6;
  const int m0   = blockIdx.x * GBM;

  f32x4 acc[8];
  #pragma unroll
  for (int i = 0; i < 8; i++) acc[i] = (f32x4){0.f, 0.f, 0.f, 0.f};

  const int arow   = m0 + w * 16 + (lane & 15);
  const int arow_c = arow < M ? arow : (M - 1);
  const float* __restrict__ Xrow = X + (size_t)arow_c * K;
  const int kgrp = (lane >> 4) * 8;          // 0,8,16,24

  const int sg = tid & 7, snb = tid >> 3;    // staging coords

  for (int k0 = 0; k0 < Kpad; k0 += GBK) {
    #pragma unroll
    for (int i = 0; i < 4; i++) {
      int n = snb + 32 * i;
      f16x8 v = *(const f16x8*)(Wt + (size_t)n * Kpad + k0 + sg * 8);
      int kt = sg >> 2, nt = n >> 4;
      int fl = (n & 15) + (sg & 3) * 16;
      *(f16x8*)&Bl[((kt * 8 + nt) * 64 + fl) * 8] = v;
    }
    __syncthreads();
    const bool fast = (k0 + GBK <= K);
    #pragma unroll
    for (int kt = 0; kt < 2; kt++) {
      int kb = k0 + kt * 32 + kgrp;
      f16x8 af;
      if (fast) {
        #pragma unroll
        for (int j = 0; j < 8; j++) af[j] = (_Float16)Xrow[kb + j];
      } else {
        #pragma unroll
        for (int j = 0; j < 8; j++)
          af[j] = (kb + j < K) ? (_Float16)Xrow[kb + j] : (_Float16)0.f;
      }
      #pragma unroll
      for (int nt = 0; nt < 8; nt++) {
        f16x8 bf = *(const f16x8*)&Bl[((kt * 8 + nt) * 64 + lane) * 8];
        acc[nt] = __builtin_amdgcn_mfma_f32_16x16x32_f16(af, bf, acc[nt], 0, 0, 0);
      }
    }
    __syncthreads();
  }

  const int rbase = m0 + w * 16 + (lane >> 4) * 4;
  const int col   = lane & 15;
  #pragma unroll
  for (int r = 0; r < 4; r++) {
    int gm = rbase + r;
    if (gm < M) {
      #pragma unroll
      for (int nt = 0; nt < 8; nt++)
        H16[(size_t)gm * FH + nt * 16 + col] = __float2half(acc[nt][r]);
    }
  }
}

// ---------------- a_s = h . as, a_d = h . ad (wave per node, fp16 H) ------------
__global__ void av16_kernel(const __half* __restrict__ H16, const float* __restrict__ avs,
                            const float* __restrict__ avd,
                            float* __restrict__ a_s, float* __restrict__ a_d, int N) {
  int gid = blockIdx.x * 256 + threadIdx.x;
  int node = gid >> 6, lane = threadIdx.x & 63;
  if (node >= N) return;
  float2 h  = __half22float2(((const __half2*)H16)[(size_t)node * 64 + lane]);
  float2 vs = *(const float2*)&avs[lane * 2];
  float2 vd = *(const float2*)&avd[lane * 2];
  float s = h.x * vs.x + h.y * vs.y;
  float d = h.x * vd.x + h.y * vd.y;
  for (int off = 32; off; off >>= 1) { s += __shfl_down(s, off); d += __shfl_down(d, off); }
  if (lane == 0) { a_s[node] = s; a_d[node] = d; }
}

// ---------------- GAT aggregation: single-pass, packed CSR, inline easum --------
__global__ void agg_kernel(const __half* __restrict__ H16, const int* __restrict__ rowptr,
                           const unsigned int* __restrict__ pack,
                           const float* __restrict__ a_s, const float* __restrict__ a_d,
                           const float* __restrict__ cv, int cidx,
                           const float* __restrict__ bias,
                           float* __restrict__ Hout, int N) {
  int gid = blockIdx.x * 256 + threadIdx.x;
  int node = gid >> 6, lane = threadIdx.x & 63;
  if (node >= N) return;
  const __half2* __restrict__ H2 = (const __half2*)H16;   // row stride 64 half2
  const float c   = cv[cidx];
  const float adn = a_d[node];
  const int beg = rowptr[node], end = rowptr[node + 1];
  float2 acc0 = make_float2(0.f, 0.f), acc1 = make_float2(0.f, 0.f);
  float den0 = 0.f, den1 = 0.f;
  float ea_tot = 0.f;
  int p = beg;
  for (; p + 3 < end; p += 4) {
    unsigned w0 = pack[p],     w1 = pack[p + 1];
    unsigned w2 = pack[p + 2], w3 = pack[p + 3];
    int s0 = w0 >> 16, s1 = w1 >> 16, s2 = w2 >> 16, s3 = w3 >> 16;
    __half2 g0 = H2[(size_t)s0 * 64 + lane];
    __half2 g1 = H2[(size_t)s1 * 64 + lane];
    __half2 g2 = H2[(size_t)s2 * 64 + lane];
    __half2 g3 = H2[(size_t)s3 * 64 + lane];
    float e0 = __half2float(__ushort_as_half((unsigned short)(w0 & 0xffff)));
    float e1 = __half2float(__ushort_as_half((unsigned short)(w1 & 0xffff)));
    float e2 = __half2float(__ushort_as_half((unsigned short)(w2 & 0xffff)));
    float e3 = __half2float(__ushort_as_half((unsigned short)(w3 & 0xffff)));
    float al0 = a_s[s0] + adn + c * e0;
    float al1 = a_s[s1] + adn + c * e1;
    float al2 = a_s[s2] + adn + c * e2;
    float al3 = a_s[s3] + adn + c * e3;
    ea_tot += (e0 + e1) + (e2 + e3);
    al0 = (al0 >= 0.f) ? al0 : NEG_SLOPE * al0;
    al1 = (al1 >= 0.f) ? al1 : NEG_SLOPE * al1;
    al2 = (al2 >= 0.f) ? al2 : NEG_SLOPE * al2;
    al3 = (al3 >= 0.f) ? al3 : NEG_SLOPE * al3;
    float ex0 = __expf(al0), ex1 = __expf(al1);
    float ex2 = __expf(al2), ex3 = __expf(al3);
    float2 h0 = __half22float2(g0), h1 = __half22float2(g1);
    float2 h2 = __half22float2(g2), h3 = __half22float2(g3);
    den0 += ex0 + ex2; den1 += ex1 + ex3;
    acc0.x += ex0 * h0.x + ex2 * h2.x; acc0.y += ex0 * h0.y + ex2 * h2.y;
    acc1.x += ex1 * h1.x + ex3 * h3.x; acc1.y += ex1 * h1.y + ex3 * h3.y;
  }
  for (; p < end; p++) {
    unsigned w0 = pack[p];
    int s0 = w0 >> 16;
    float e0 = __half2float(__ushort_as_half((unsigned short)(w0 & 0xffff)));
    float al0 = a_s[s0] + adn + c * e0;
    ea_tot += e0;
    al0 = (al0 >= 0.f) ? al0 : NEG_SLOPE * al0;
    float ex0 = __expf(al0);
    float2 h0 = __half22float2(H2[(size_t)s0 * 64 + lane]);
    den0 += ex0;
    acc0.x += ex0 * h0.x; acc0.y += ex0 * h0.y;
  }
  { // self loop, ea = mean of incoming edge attrs (0 if none)
    int dg = end - beg;
    float eal = ea_tot / fmaxf((float)dg, 1.f);
    float alpha = a_s[node] + adn + c * eal;
    alpha = (alpha >= 0.f) ? alpha : NEG_SLOPE * alpha;
    float ex = __expf(alpha);
    float2 h = __half22float2(H2[(size_t)node * 64 + lane]);
    den0 += ex;
    acc0.x += ex * h.x; acc0.y += ex * h.y;
  }
  float inv = 1.f / (den0 + den1);
  float2 b = *(const float2*)&bias[lane * 2];
  float o0 = fmaxf((acc0.x + acc1.x) * inv + b.x, 0.f);   // + bias, ReLU
  float o1 = fmaxf((acc0.y + acc1.y) * inv + b.y, 0.f);
  *(float2*)&Hout[(size_t)node * FH + lane * 2] = make_float2(o0, o1);
}

// ---------------- node head: b_out and p = h.Ww ----------------------------------
__global__ void node_head_kernel(const float* __restrict__ H, const float* __restrict__ Wb,
                                 const float* __restrict__ bb, const float* __restrict__ Ww,
                                 const float* __restrict__ mask,
                                 float* __restrict__ bout, float* __restrict__ p, int N) {
  int gid = blockIdx.x * 256 + threadIdx.x;
  int node = gid >> 6, lane = threadIdx.x & 63;
  if (node >= N) return;
  float2 h  = *(const float2*)&H[(size_t)node * FH + lane * 2];
  float2 wb = *(const float2*)&Wb[lane * 2];
  float2 ww = *(const float2*)&Ww[lane * 2];
  float sb = h.x * wb.x + h.y * wb.y;
  float sw = h.x * ww.x + h.y * ww.y;
  for (int off = 32; off; off >>= 1) { sb += __shfl_down(sb, off); sw += __shfl_down(sw, off); }
  if (lane == 0) {
    bout[node] = (sb + bb[0]) * mask[node];
    p[node]    = sw;
  }
}

// ---------------- edge head: w = 0.5*(p[src]+p[dst]) + bw ------------------------
__global__ void edge_head_kernel(const int* __restrict__ ei, const float* __restrict__ p,
                                 const float* __restrict__ bw, float* __restrict__ w, int E) {
  int e = blockIdx.x * 256 + threadIdx.x;
  if (e >= E) return;
  w[e] = 0.5f * (p[ei[e]] + p[ei[E + e]]) + bw[0];
}

extern "C" void kernel_launch(void* const* d_in, const int* in_sizes, int n_in,
                              void* d_out, int out_size, void* d_ws, size_t ws_size,
                              hipStream_t stream) {
  (void)n_in; (void)out_size; (void)ws_size;
  const float* x    = (const float*)d_in[0];
  const int*   ei   = (const int*)  d_in[1];
  const float* ea   = (const float*)d_in[2];
  const float* mask = (const float*)d_in[3];
  const float* W1   = (const float*)d_in[4];
  const float* b1   = (const float*)d_in[5];
  const float* as1  = (const float*)d_in[6];
  const float* ad1  = (const float*)d_in[7];
  const float* We1  = (const float*)d_in[8];
  const float* ae1  = (const float*)d_in[9];
  const float* W2   = (const float*)d_in[10];
  const float* b2   = (const float*)d_in[11];
  const float* as2  = (const float*)d_in[12];
  const float* ad2  = (const float*)d_in[13];
  const float* We2  = (const float*)d_in[14];
  const float* ae2  = (const float*)d_in[15];
  const float* Wb   = (const float*)d_in[16];
  const float* bb   = (const float*)d_in[17];
  const float* Ww   = (const float*)d_in[18];
  const float* bw   = (const float*)d_in[19];

  const int N  = in_sizes[3];          // 50000
  const int E  = in_sizes[1] / 2;      // 1600000
  const int K1 = in_sizes[0] / N;      // 503
  const int K1p = (K1 + GBK - 1) & ~(GBK - 1);   // 512

  // ---- workspace carve-up (256B aligned) ----
  char* ws = (char*)d_ws;
  size_t off = 0;
  auto alloc = [&](size_t bytes) -> char* {
    char* q = ws + off;
    off = (off + bytes + 255) & ~(size_t)255;
    return q;
  };
  int*   cnt    = (int*)  alloc((size_t)N * 4);
  int*   rowptr = (int*)  alloc((size_t)(N + 1) * 4);
  int*   bsum   = (int*)  alloc(1024 * 4);
  unsigned short* rank = (unsigned short*)alloc((size_t)E * 2);
  unsigned int*   pack = (unsigned int*)  alloc((size_t)E * 4);
  float* a_s    = (float*)alloc((size_t)N * 4);
  float* a_d    = (float*)alloc((size_t)N * 4);
  __half* H16   = (__half*)alloc((size_t)N * FH * 2);  // fp16 GEMM out
  float* HB     = (float*)alloc((size_t)N * FH * 4);   // agg out (f32)
  float* pbuf   = (float*)alloc((size_t)N * 4);
  float* cv     = (float*)alloc(8);
  __half* W1t   = (__half*)alloc((size_t)FH * K1p * 2);
  __half* W2t   = (__half*)alloc((size_t)FH * FH * 2);

  float* w_out = (float*)d_out;        // [E]
  float* b_out = (float*)d_out + E;    // [N]

  hipMemsetAsync(cnt, 0, (size_t)N * 4, stream);

  const int eb  = (E + 255) / 256;
  const int nb  = (N + 255) / 256;
  const int gb  = (N + GBM - 1) / GBM;
  const int wbk = ((size_t)N * 64 + 255) / 256;   // wave-per-node launches

  // topology precompute (shared by both layers): ONE atomic pass
  rank_kernel  <<<eb, 256, 0, stream>>>(ei, cnt, rank, E);
  scan_blocksum<<<nb, 256, 0, stream>>>(cnt, bsum, N);
  scan_bsum    <<<1, 1024, 0, stream>>>(bsum, nb, rowptr, N);
  scan_final   <<<nb, 256, 0, stream>>>(cnt, bsum, rowptr, N);
  place_kernel <<<eb, 256, 0, stream>>>(ei, ea, rowptr, rank, pack, E);
  cvec_kernel  <<<1, 64, 0, stream>>>(We1, ae1, We2, ae2, cv);
  wcvt_kernel  <<<(128 * K1p + 255) / 256, 256, 0, stream>>>(W1, W1t, K1, K1p);
  wcvt_kernel  <<<(128 * FH + 255) / 256, 256, 0, stream>>>(W2, W2t, FH, FH);

  // layer 1
  mfma_gemm_kernel<<<gb, 256, 0, stream>>>(x, W1t, H16, N, K1, K1p);
  av16_kernel <<<wbk, 256, 0, stream>>>(H16, as1, ad1, a_s, a_d, N);
  agg_kernel  <<<wbk, 256, 0, stream>>>(H16, rowptr, pack, a_s, a_d, cv, 0, b1, HB, N);
  // layer 2
  mfma_gemm_kernel<<<gb, 256, 0, stream>>>(HB, W2t, H16, N, FH, FH);
  av16_kernel <<<wbk, 256, 0, stream>>>(H16, as2, ad2, a_s, a_d, N);
  agg_kernel  <<<wbk, 256, 0, stream>>>(H16, rowptr, pack, a_s, a_d, cv, 1, b2, HB, N);
  // heads (HB holds layer-2 output, f32)
  node_head_kernel<<<wbk, 256, 0, stream>>>(HB, Wb, bb, Ww, mask, b_out, pbuf, N);
  edge_head_kernel<<<eb, 256, 0, stream>>>(ei, pbuf, bw, w_out, E);
}

// Round 6
// 313.450 us; speedup vs baseline: 2.9733x; 1.1049x over previous
//
#include <hip/hip_runtime.h>
#include <hip/hip_fp16.h>

#define FH 128
#define NEG_SLOPE 0.2f
#define GBM 64
#define GBK 64

typedef _Float16 f16x8 __attribute__((ext_vector_type(8)));
typedef float f32x4 __attribute__((ext_vector_type(4)));

// ---------------- pass A: rank[e] = running count per dst (ONE atomic/edge) -----
__global__ void rank_kernel(const int* __restrict__ ei, int* __restrict__ cnt,
                            unsigned short* __restrict__ rank, int E) {
  int e = blockIdx.x * 256 + threadIdx.x;
  if (e >= E) return;
  int dst = ei[E + e];
  rank[e] = (unsigned short)atomicAdd(&cnt[dst], 1);
}

// ---------------- 3-kernel exclusive scan of cnt -> rowptr ----------------------
__global__ void scan_blocksum(const int* __restrict__ deg, int* __restrict__ bsum, int n) {
  __shared__ int sm[256];
  int i = blockIdx.x * 256 + threadIdx.x;
  sm[threadIdx.x] = (i < n) ? deg[i] : 0;
  __syncthreads();
  for (int off = 128; off > 0; off >>= 1) {
    if (threadIdx.x < off) sm[threadIdx.x] += sm[threadIdx.x + off];
    __syncthreads();
  }
  if (threadIdx.x == 0) bsum[blockIdx.x] = sm[0];
}

__global__ void scan_bsum(int* __restrict__ bsum, int nb, int* __restrict__ rowptr, int N) {
  __shared__ int sm[1024];
  int t = threadIdx.x;
  int v = (t < nb) ? bsum[t] : 0;
  sm[t] = v;
  __syncthreads();
  for (int off = 1; off < 1024; off <<= 1) {
    int u = (t >= off) ? sm[t - off] : 0;
    __syncthreads();
    sm[t] += u;
    __syncthreads();
  }
  if (t < nb) bsum[t] = sm[t] - v;   // exclusive block offsets
  if (t == 1023) rowptr[N] = sm[1023];
}

__global__ void scan_final(const int* __restrict__ deg, const int* __restrict__ bsum,
                           int* __restrict__ rowptr, int n) {
  __shared__ int sm[256];
  int i = blockIdx.x * 256 + threadIdx.x;
  int v = (i < n) ? deg[i] : 0;
  sm[threadIdx.x] = v;
  __syncthreads();
  for (int off = 1; off < 256; off <<= 1) {
    int u = (threadIdx.x >= off) ? sm[threadIdx.x - off] : 0;
    __syncthreads();
    sm[threadIdx.x] += u;
    __syncthreads();
  }
  if (i < n) rowptr[i] = bsum[blockIdx.x] + sm[threadIdx.x] - v;
}

// ---------------- pass B: atomic-free CSR placement, packed 4B entries ----------
// entry = (src << 16) | fp16(ea)   [N=50000 < 2^16]
__global__ void place_kernel(const int* __restrict__ ei, const float* __restrict__ ea,
                             const int* __restrict__ rowptr,
                             const unsigned short* __restrict__ rank,
                             unsigned int* __restrict__ pack, int E) {
  int e = blockIdx.x * 256 + threadIdx.x;
  if (e >= E) return;
  int src = ei[e], dst = ei[E + e];
  int pos = rowptr[dst] + rank[e];
  unsigned short h = __half_as_ushort(__float2half(ea[e]));
  pack[pos] = ((unsigned int)src << 16) | h;
}

// ---------------- c = We . ae (scalar per layer) --------------------------------
__global__ void cvec_kernel(const float* __restrict__ We1, const float* __restrict__ ae1,
                            const float* __restrict__ We2, const float* __restrict__ ae2,
                            float* __restrict__ cv) {
  int l = threadIdx.x;  // 64 lanes
  float s1 = We1[l] * ae1[l] + We1[l + 64] * ae1[l + 64];
  float s2 = We2[l] * ae2[l] + We2[l + 64] * ae2[l + 64];
  for (int off = 32; off; off >>= 1) { s1 += __shfl_down(s1, off); s2 += __shfl_down(s2, off); }
  if (l == 0) { cv[0] = s1; cv[1] = s2; }
}

// ---------------- W (K x 128) -> Wt fp16 [128][Kpad] (transposed, zero-padded) ---
__global__ void wcvt_kernel(const float* __restrict__ W, __half* __restrict__ Wt,
                            int K, int Kpad) {
  int idx = blockIdx.x * 256 + threadIdx.x;
  if (idx >= 128 * Kpad) return;
  int n = idx / Kpad, k = idx - n * Kpad;
  Wt[idx] = (k < K) ? __float2half(W[(size_t)k * 128 + n]) : __float2half(0.f);
}

// ---------------- MFMA fp16 GEMM + fused a_s/a_d --------------------------------
// H16[M][128] = X[M][K] @ Wt^T; a_s/a_d from f32 accumulators (16-lane reduce).
__global__ __launch_bounds__(256, 4) void mfma_gemm_kernel(
    const float* __restrict__ X, const __half* __restrict__ Wt_,
    const float* __restrict__ avs, const float* __restrict__ avd,
    __half* __restrict__ H16, float* __restrict__ a_s, float* __restrict__ a_d,
    int M, int K, int Kpad) {
  __shared__ _Float16 Bl[2 * 8 * 64 * 8];   // [kt][nt][frag-lane][j] = 16 KB
  const _Float16* __restrict__ Wt = (const _Float16*)Wt_;
  const int tid  = threadIdx.x;
  const int lane = tid & 63;
  const int w    = tid >> 6;
  const int m0   = blockIdx.x * GBM;

  f32x4 acc[8];
  #pragma unroll
  for (int i = 0; i < 8; i++) acc[i] = (f32x4){0.f, 0.f, 0.f, 0.f};

  const int arow   = m0 + w * 16 + (lane & 15);
  const int arow_c = arow < M ? arow : (M - 1);
  const float* __restrict__ Xrow = X + (size_t)arow_c * K;
  const int kgrp = (lane >> 4) * 8;          // 0,8,16,24

  const int sg = tid & 7, snb = tid >> 3;    // staging coords

  for (int k0 = 0; k0 < Kpad; k0 += GBK) {
    #pragma unroll
    for (int i = 0; i < 4; i++) {
      int n = snb + 32 * i;
      f16x8 v = *(const f16x8*)(Wt + (size_t)n * Kpad + k0 + sg * 8);
      int kt = sg >> 2, nt = n >> 4;
      int fl = (n & 15) + (sg & 3) * 16;
      *(f16x8*)&Bl[((kt * 8 + nt) * 64 + fl) * 8] = v;
    }
    __syncthreads();
    const bool fast = (k0 + GBK <= K);
    #pragma unroll
    for (int kt = 0; kt < 2; kt++) {
      int kb = k0 + kt * 32 + kgrp;
      f16x8 af;
      if (fast) {
        #pragma unroll
        for (int j = 0; j < 8; j++) af[j] = (_Float16)Xrow[kb + j];
      } else {
        #pragma unroll
        for (int j = 0; j < 8; j++)
          af[j] = (kb + j < K) ? (_Float16)Xrow[kb + j] : (_Float16)0.f;
      }
      #pragma unroll
      for (int nt = 0; nt < 8; nt++) {
        f16x8 bf = *(const f16x8*)&Bl[((kt * 8 + nt) * 64 + lane) * 8];
        acc[nt] = __builtin_amdgcn_mfma_f32_16x16x32_f16(af, bf, acc[nt], 0, 0, 0);
      }
    }
    __syncthreads();
  }

  // C store (fp16) + fused per-row dots with avs/avd (f32 accuracy)
  const int rbase = m0 + w * 16 + (lane >> 4) * 4;
  const int col   = lane & 15;
  float as_v[8], ad_v[8];
  #pragma unroll
  for (int nt = 0; nt < 8; nt++) {
    as_v[nt] = avs[nt * 16 + col];
    ad_v[nt] = avd[nt * 16 + col];
  }
  #pragma unroll
  for (int r = 0; r < 4; r++) {
    int gm = rbase + r;
    float ps = 0.f, pd = 0.f;
    #pragma unroll
    for (int nt = 0; nt < 8; nt++) {
      ps += acc[nt][r] * as_v[nt];
      pd += acc[nt][r] * ad_v[nt];
    }
    #pragma unroll
    for (int msk = 1; msk < 16; msk <<= 1) {
      ps += __shfl_xor(ps, msk);
      pd += __shfl_xor(pd, msk);
    }
    if (gm < M) {
      #pragma unroll
      for (int nt = 0; nt < 8; nt++)
        H16[(size_t)gm * FH + nt * 16 + col] = __float2half(acc[nt][r]);
      if (col == 0) { a_s[gm] = ps; a_d[gm] = pd; }
    }
  }
}

// ---------------- GAT aggregation: wave/node, 4 slots x 16 lanes ----------------
// Each slot takes every-4th edge; lane covers 8 features (16B half8 gather).
// Scalar per-edge work now runs at 16x redundancy (4 distinct edges per wave-inst).
__global__ __launch_bounds__(256) void agg_kernel(
    const __half* __restrict__ H16, const int* __restrict__ rowptr,
    const unsigned int* __restrict__ pack,
    const float* __restrict__ a_s, const float* __restrict__ a_d,
    const float* __restrict__ cv, int cidx,
    const float* __restrict__ bias,
    float* __restrict__ Hout, int N) {
  const int node = (blockIdx.x * 256 + threadIdx.x) >> 6;
  const int lane = threadIdx.x & 63;
  const int slot = lane >> 4, sl = lane & 15;
  if (node >= N) return;
  const _Float16* __restrict__ Hh = (const _Float16*)H16;
  const float c   = cv[cidx];
  const float adn = a_d[node];
  const int beg = rowptr[node], end = rowptr[node + 1];

  float acc[8] = {0.f, 0.f, 0.f, 0.f, 0.f, 0.f, 0.f, 0.f};
  float den = 0.f, ea_tot = 0.f;

  for (int p = beg + slot; p < end; p += 4) {
    unsigned w0 = pack[p];
    int s0 = w0 >> 16;
    float e0 = __half2float(__ushort_as_half((unsigned short)(w0 & 0xffff)));
    float al = a_s[s0] + adn + c * e0;
    al = fmaxf(al, NEG_SLOPE * al);         // leaky_relu, branchless
    float ex = __expf(al);
    f16x8 h = *(const f16x8*)(Hh + (size_t)s0 * FH + sl * 8);
    ea_tot += e0;
    den += ex;
    #pragma unroll
    for (int j = 0; j < 8; j++) acc[j] += ex * (float)h[j];
  }
  // cross-slot reduce (slots differ in lane bits 4,5)
  ea_tot += __shfl_xor(ea_tot, 16); ea_tot += __shfl_xor(ea_tot, 32);
  den    += __shfl_xor(den,    16); den    += __shfl_xor(den,    32);
  #pragma unroll
  for (int j = 0; j < 8; j++) {
    acc[j] += __shfl_xor(acc[j], 16);
    acc[j] += __shfl_xor(acc[j], 32);
  }
  { // self loop, ea = mean of incoming edge attrs (0 if none); uniform across lanes
    int dg = end - beg;
    float eal = ea_tot / fmaxf((float)dg, 1.f);
    float al = a_s[node] + adn + c * eal;
    al = fmaxf(al, NEG_SLOPE * al);
    float ex = __expf(al);
    f16x8 h = *(const f16x8*)(Hh + (size_t)node * FH + sl * 8);
    den += ex;
    #pragma unroll
    for (int j = 0; j < 8; j++) acc[j] += ex * (float)h[j];
  }
  if (slot == 0) {
    float inv = 1.f / den;
    float4 b0 = *(const float4*)&bias[sl * 8];
    float4 b1 = *(const float4*)&bias[sl * 8 + 4];
    float4 o0, o1;
    o0.x = fmaxf(acc[0] * inv + b0.x, 0.f);
    o0.y = fmaxf(acc[1] * inv + b0.y, 0.f);
    o0.z = fmaxf(acc[2] * inv + b0.z, 0.f);
    o0.w = fmaxf(acc[3] * inv + b0.w, 0.f);
    o1.x = fmaxf(acc[4] * inv + b1.x, 0.f);
    o1.y = fmaxf(acc[5] * inv + b1.y, 0.f);
    o1.z = fmaxf(acc[6] * inv + b1.z, 0.f);
    o1.w = fmaxf(acc[7] * inv + b1.w, 0.f);
    *(float4*)&Hout[(size_t)node * FH + sl * 8]     = o0;
    *(float4*)&Hout[(size_t)node * FH + sl * 8 + 4] = o1;
  }
}

// ---------------- node head: b_out and p = h.Ww ----------------------------------
__global__ void node_head_kernel(const float* __restrict__ H, const float* __restrict__ Wb,
                                 const float* __restrict__ bb, const float* __restrict__ Ww,
                                 const float* __restrict__ mask,
                                 float* __restrict__ bout, float* __restrict__ p, int N) {
  int gid = blockIdx.x * 256 + threadIdx.x;
  int node = gid >> 6, lane = threadIdx.x & 63;
  if (node >= N) return;
  float2 h  = *(const float2*)&H[(size_t)node * FH + lane * 2];
  float2 wb = *(const float2*)&Wb[lane * 2];
  float2 ww = *(const float2*)&Ww[lane * 2];
  float sb = h.x * wb.x + h.y * wb.y;
  float sw = h.x * ww.x + h.y * ww.y;
  for (int off = 32; off; off >>= 1) { sb += __shfl_down(sb, off); sw += __shfl_down(sw, off); }
  if (lane == 0) {
    bout[node] = (sb + bb[0]) * mask[node];
    p[node]    = sw;
  }
}

// ---------------- edge head: w = 0.5*(p[src]+p[dst]) + bw, x4 vectorized ---------
__global__ void edge_head_kernel(const int* __restrict__ ei, const float* __restrict__ p,
                                 const float* __restrict__ bw, float* __restrict__ w, int E) {
  int base = (blockIdx.x * 256 + threadIdx.x) * 4;
  if (base >= E) return;
  float b = bw[0];
  if (base + 4 <= E && (E & 3) == 0) {
    int4 s = *(const int4*)&ei[base];
    int4 d = *(const int4*)&ei[E + base];
    float4 o;
    o.x = 0.5f * (p[s.x] + p[d.x]) + b;
    o.y = 0.5f * (p[s.y] + p[d.y]) + b;
    o.z = 0.5f * (p[s.z] + p[d.z]) + b;
    o.w = 0.5f * (p[s.w] + p[d.w]) + b;
    *(float4*)&w[base] = o;
  } else {
    for (int e = base; e < E && e < base + 4; e++)
      w[e] = 0.5f * (p[ei[e]] + p[ei[E + e]]) + b;
  }
}

extern "C" void kernel_launch(void* const* d_in, const int* in_sizes, int n_in,
                              void* d_out, int out_size, void* d_ws, size_t ws_size,
                              hipStream_t stream) {
  (void)n_in; (void)out_size; (void)ws_size;
  const float* x    = (const float*)d_in[0];
  const int*   ei   = (const int*)  d_in[1];
  const float* ea   = (const float*)d_in[2];
  const float* mask = (const float*)d_in[3];
  const float* W1   = (const float*)d_in[4];
  const float* b1   = (const float*)d_in[5];
  const float* as1  = (const float*)d_in[6];
  const float* ad1  = (const float*)d_in[7];
  const float* We1  = (const float*)d_in[8];
  const float* ae1  = (const float*)d_in[9];
  const float* W2   = (const float*)d_in[10];
  const float* b2   = (const float*)d_in[11];
  const float* as2  = (const float*)d_in[12];
  const float* ad2  = (const float*)d_in[13];
  const float* We2  = (const float*)d_in[14];
  const float* ae2  = (const float*)d_in[15];
  const float* Wb   = (const float*)d_in[16];
  const float* bb   = (const float*)d_in[17];
  const float* Ww   = (const float*)d_in[18];
  const float* bw   = (const float*)d_in[19];

  const int N  = in_sizes[3];          // 50000
  const int E  = in_sizes[1] / 2;      // 1600000
  const int K1 = in_sizes[0] / N;      // 503
  const int K1p = (K1 + GBK - 1) & ~(GBK - 1);   // 512

  // ---- workspace carve-up (256B aligned) ----
  char* ws = (char*)d_ws;
  size_t off = 0;
  auto alloc = [&](size_t bytes) -> char* {
    char* q = ws + off;
    off = (off + bytes + 255) & ~(size_t)255;
    return q;
  };
  int*   cnt    = (int*)  alloc((size_t)N * 4);
  int*   rowptr = (int*)  alloc((size_t)(N + 1) * 4);
  int*   bsum   = (int*)  alloc(1024 * 4);
  unsigned short* rank = (unsigned short*)alloc((size_t)E * 2);
  unsigned int*   pack = (unsigned int*)  alloc((size_t)E * 4);
  float* a_s    = (float*)alloc((size_t)N * 4);
  float* a_d    = (float*)alloc((size_t)N * 4);
  __half* H16   = (__half*)alloc((size_t)N * FH * 2);  // fp16 GEMM out
  float* HB     = (float*)alloc((size_t)N * FH * 4);   // agg out (f32)
  float* pbuf   = (float*)alloc((size_t)N * 4);
  float* cv     = (float*)alloc(8);
  __half* W1t   = (__half*)alloc((size_t)FH * K1p * 2);
  __half* W2t   = (__half*)alloc((size_t)FH * FH * 2);

  float* w_out = (float*)d_out;        // [E]
  float* b_out = (float*)d_out + E;    // [N]

  hipMemsetAsync(cnt, 0, (size_t)N * 4, stream);

  const int eb  = (E + 255) / 256;
  const int nb  = (N + 255) / 256;
  const int gb  = (N + GBM - 1) / GBM;
  const int wbk = ((size_t)N * 64 + 255) / 256;   // wave-per-node launches
  const int ab  = (N + 3) / 4;                    // agg: 4 nodes/block
  const int ehb = (E + 1023) / 1024;              // edge head: 4 edges/thread

  // topology precompute (shared by both layers): ONE atomic pass
  rank_kernel  <<<eb, 256, 0, stream>>>(ei, cnt, rank, E);
  scan_blocksum<<<nb, 256, 0, stream>>>(cnt, bsum, N);
  scan_bsum    <<<1, 1024, 0, stream>>>(bsum, nb, rowptr, N);
  scan_final   <<<nb, 256, 0, stream>>>(cnt, bsum, rowptr, N);
  place_kernel <<<eb, 256, 0, stream>>>(ei, ea, rowptr, rank, pack, E);
  cvec_kernel  <<<1, 64, 0, stream>>>(We1, ae1, We2, ae2, cv);
  wcvt_kernel  <<<(128 * K1p + 255) / 256, 256, 0, stream>>>(W1, W1t, K1, K1p);
  wcvt_kernel  <<<(128 * FH + 255) / 256, 256, 0, stream>>>(W2, W2t, FH, FH);

  // layer 1 (GEMM fused with a_s/a_d)
  mfma_gemm_kernel<<<gb, 256, 0, stream>>>(x, W1t, as1, ad1, H16, a_s, a_d, N, K1, K1p);
  agg_kernel  <<<ab, 256, 0, stream>>>(H16, rowptr, pack, a_s, a_d, cv, 0, b1, HB, N);
  // layer 2
  mfma_gemm_kernel<<<gb, 256, 0, stream>>>(HB, W2t, as2, ad2, H16, a_s, a_d, N, FH, FH);
  agg_kernel  <<<ab, 256, 0, stream>>>(H16, rowptr, pack, a_s, a_d, cv, 1, b2, HB, N);
  // heads (HB holds layer-2 output, f32)
  node_head_kernel<<<wbk, 256, 0, stream>>>(HB, Wb, bb, Ww, mask, b_out, pbuf, N);
  edge_head_kernel<<<ehb, 256, 0, stream>>>(ei, pbuf, bw, w_out, E);
}